// Round 8
// baseline (400.571 us; speedup 1.0000x reference)
//
#include <hip/hip_runtime.h>
#include <math.h>

#define N_NODES 50000
#define E_EDGES 800000
#define KD 128
#define NBLK_SCAN 196   // ceil(50000/256)
#define RT_TILES 3125   // N_NODES / 16 (exact)

typedef __attribute__((ext_vector_type(8))) short bf16x8;
typedef __attribute__((ext_vector_type(4))) float f32x4;

__device__ __forceinline__ float fsig(float x) { return 1.f / (1.f + __expf(-x)); }
__device__ __forceinline__ float ftanh(float x) { return 1.f - 2.f / (1.f + __expf(2.f * x)); }

__device__ __forceinline__ unsigned short f2bf(float f) {
    unsigned u = __float_as_uint(f);
    return (unsigned short)((u + 0x7FFFu + ((u >> 16) & 1u)) >> 16);
}
__device__ __forceinline__ float bf2f(unsigned short b) {
    return __uint_as_float(((unsigned)b) << 16);
}
__device__ __forceinline__ bf16x8 ldfrag(const unsigned short* p) {
    return *(const bf16x8*)(const void*)p;
}
__device__ __forceinline__ void stage_frag(const unsigned short* g, unsigned short* l) {
    __builtin_amdgcn_global_load_lds(
        (const __attribute__((address_space(1))) unsigned int*)g,
        (__attribute__((address_space(3))) unsigned int*)l, 16, 0, 0);
}

// ---------------------------------------------------------------------------
// fp32 -> bf16 converts
// ---------------------------------------------------------------------------
__global__ __launch_bounds__(256) void cvt_xh(const float* __restrict__ x,
                                              const float* __restrict__ H,
                                              unsigned short* __restrict__ hb,
                                              unsigned short* __restrict__ Hxb, int n4) {
    int t = blockIdx.x * 256 + threadIdx.x;
    const float* in; unsigned short* out; int idx;
    if (t < n4) { in = x; out = hb; idx = t; }
    else if (t < 2 * n4) { in = H; out = Hxb; idx = t - n4; }
    else return;
    float4 v = ((const float4*)in)[idx];
    ushort4 o;
    o.x = f2bf(v.x); o.y = f2bf(v.y); o.z = f2bf(v.z); o.w = f2bf(v.w);
    ((ushort4*)out)[idx] = o;
}

__global__ __launch_bounds__(256) void cvt_weights(
        const float* __restrict__ a, const float* __restrict__ b,
        const float* __restrict__ c, const float* __restrict__ d,
        const float* __restrict__ e,
        unsigned short* __restrict__ oa, unsigned short* __restrict__ ob,
        unsigned short* __restrict__ oc, unsigned short* __restrict__ od,
        unsigned short* __restrict__ oe) {
    int t = blockIdx.x * 256 + threadIdx.x;
    const float* in; unsigned short* out; int idx;
    if      (t < 12288)  { in = a; out = oa; idx = t; }
    else if (t < 24576)  { in = b; out = ob; idx = t - 12288; }
    else if (t < 40960)  { in = c; out = oc; idx = t - 24576; }
    else if (t < 57344)  { in = d; out = od; idx = t - 40960; }
    else if (t < 59392)  { in = e; out = oe; idx = t - 57344; }
    else return;
    float4 v = ((const float4*)in)[idx];
    ushort4 o;
    o.x = f2bf(v.x); o.y = f2bf(v.y); o.z = f2bf(v.z); o.w = f2bf(v.w);
    ((ushort4*)out)[idx] = o;
}

__global__ __launch_bounds__(256) void transpose_wg_bf16(const float* __restrict__ W,
                                                         unsigned short* __restrict__ WT) {
    int t = blockIdx.x * 256 + threadIdx.x;
    int l = t >> 14;
    int r = (t >> 7) & 127;
    int c = t & 127;
    WT[l * 16384 + c * 128 + r] = f2bf(W[l * 16384 + r * 128 + c]);
}

// ---------------------------------------------------------------------------
// CSR build
// ---------------------------------------------------------------------------
__global__ __launch_bounds__(256) void count_deg(const int* __restrict__ ei,
                                                 int* __restrict__ deg) {
    int e = blockIdx.x * 256 + threadIdx.x;
    if (e >= E_EDGES) return;
    atomicAdd(&deg[ei[E_EDGES + e]], 1);
}

__global__ __launch_bounds__(256) void scan_p1(const int* __restrict__ deg,
                                               int* __restrict__ excl,
                                               int* __restrict__ bsum) {
    __shared__ int part[256];
    const int t = threadIdx.x;
    const int i = blockIdx.x * 256 + t;
    int v = (i < N_NODES) ? deg[i] : 0;
    part[t] = v;
    __syncthreads();
#pragma unroll
    for (int off = 1; off < 256; off <<= 1) {
        int u = (t >= off) ? part[t - off] : 0;
        __syncthreads();
        part[t] += u;
        __syncthreads();
    }
    if (i < N_NODES) excl[i] = part[t] - v;
    if (t == 255) bsum[blockIdx.x] = part[255];
}

__global__ __launch_bounds__(256) void scan_p2(int* __restrict__ bsum,
                                               int* __restrict__ rowptrN) {
    __shared__ int part[256];
    const int t = threadIdx.x;
    int v = (t < NBLK_SCAN) ? bsum[t] : 0;
    part[t] = v;
    __syncthreads();
#pragma unroll
    for (int off = 1; off < 256; off <<= 1) {
        int u = (t >= off) ? part[t - off] : 0;
        __syncthreads();
        part[t] += u;
        __syncthreads();
    }
    if (t < NBLK_SCAN) bsum[t] = part[t] - v;
    if (t == 255) *rowptrN = part[255];
}

__global__ __launch_bounds__(256) void scan_p3(const int* __restrict__ bsum,
                                               int* __restrict__ rowptr,
                                               int* __restrict__ cursor) {
    int i = blockIdx.x * 256 + threadIdx.x;
    if (i >= N_NODES) return;
    int r = rowptr[i] + bsum[blockIdx.x];
    rowptr[i] = r;
    cursor[i] = r;
}

__global__ __launch_bounds__(256) void fill_csr(const int* __restrict__ ei,
                                                const float* __restrict__ ew,
                                                int* __restrict__ cursor,
                                                int* __restrict__ sSrc,
                                                float* __restrict__ sW) {
    int e = blockIdx.x * 256 + threadIdx.x;
    if (e >= E_EDGES) return;
    int dst = ei[E_EDGES + e];
    int pos = atomicAdd(&cursor[dst], 1);
    sSrc[pos] = ei[e];
    sW[pos] = ew[e];
}

// ---------------------------------------------------------------------------
// agg[n,:] = sum_e w[e]*m[src[e],:]; one node/wave, index prefetch
// ---------------------------------------------------------------------------
__global__ __launch_bounds__(256) void gather_agg_bf16(const unsigned short* __restrict__ m,
                                                       const int* __restrict__ rowptr,
                                                       const int* __restrict__ sSrc,
                                                       const float* __restrict__ sW,
                                                       unsigned short* __restrict__ agg) {
    int wid = (blockIdx.x * 256 + threadIdx.x) >> 6;
    if (wid >= N_NODES) return;
    int lane = threadIdx.x & 63;
    int half = lane >> 5, li = lane & 31;
    int f0 = li << 2;
    int e0 = rowptr[wid], e1 = rowptr[wid + 1];
    float ax = 0.f, ay = 0.f, az = 0.f, aw = 0.f;
    int e = e0 + half;
    int s_nx = 0; float w_nx = 0.f;
    if (e < e1) { s_nx = sSrc[e]; w_nx = sW[e]; }
    for (; e < e1; e += 2) {
        int s = s_nx; float ww = w_nx;
        int en = e + 2;
        if (en < e1) { s_nx = sSrc[en]; w_nx = sW[en]; }
        ushort4 v = *(const ushort4*)(m + (size_t)s * KD + f0);
        ax += ww * bf2f(v.x); ay += ww * bf2f(v.y);
        az += ww * bf2f(v.z); aw += ww * bf2f(v.w);
    }
    ax += __shfl_xor(ax, 32, 64);
    ay += __shfl_xor(ay, 32, 64);
    az += __shfl_xor(az, 32, 64);
    aw += __shfl_xor(aw, 32, 64);
    if (half == 0) {
        ushort4 o;
        o.x = f2bf(ax); o.y = f2bf(ay); o.z = f2bf(az); o.w = f2bf(aw);
        *(ushort4*)(agg + (size_t)wid * KD + f0) = o;
    }
}

// ---------------------------------------------------------------------------
// m = h @ Wg. Weights staged once; pipelined grid-stride over row tiles.
// ---------------------------------------------------------------------------
__global__ __launch_bounds__(256) void mfma_gemm_m(const unsigned short* __restrict__ A,
                                                   const unsigned short* __restrict__ WT,
                                                   unsigned short* __restrict__ Mout) {
    __shared__ unsigned short wlds[32 * 512];
    const int lane = threadIdx.x & 63, wave = threadIdx.x >> 6;
    const int rl = lane & 15, kg = lane >> 4;
    for (int f = wave; f < 32; f += 4) {
        int jt = f >> 2, kk = f & 3;
        stage_frag(WT + (size_t)(jt * 16 + rl) * KD + kk * 32 + kg * 8, wlds + f * 512);
    }
    __syncthreads();
    const int stride = gridDim.x << 2;
    int rt = blockIdx.x * 4 + wave;
    if (rt >= RT_TILES) return;
    bf16x8 a[4];
#pragma unroll
    for (int kk = 0; kk < 4; ++kk)
        a[kk] = ldfrag(A + ((size_t)rt * 16 + rl) * KD + kk * 32 + kg * 8);
    while (rt < RT_TILES) {
        const int rtn = rt + stride;
        bf16x8 an[4];
        if (rtn < RT_TILES) {
#pragma unroll
            for (int kk = 0; kk < 4; ++kk)
                an[kk] = ldfrag(A + ((size_t)rtn * 16 + rl) * KD + kk * 32 + kg * 8);
        }
#pragma unroll
        for (int jt = 0; jt < 8; ++jt) {
            f32x4 acc = {0.f, 0.f, 0.f, 0.f};
#pragma unroll
            for (int kk = 0; kk < 4; ++kk)
                acc = __builtin_amdgcn_mfma_f32_16x16x32_bf16(
                    a[kk], ldfrag(wlds + (jt * 4 + kk) * 512 + lane * 8), acc, 0, 0, 0);
            int col = jt * 16 + rl;
#pragma unroll
            for (int p = 0; p < 4; ++p)
                Mout[(size_t)(rt * 16 + kg * 4 + p) * KD + col] = f2bf(acc[p]);
        }
        rt = rtn;
#pragma unroll
        for (int kk = 0; kk < 4; ++kk) a[kk] = an[kk];
    }
}

// ---------------------------------------------------------------------------
// Fused GRU, col-split 4: block owns 32 output cols (2 subtiles of 16);
// 48 KB weight slice staged once; grid(x=colgrp, y=rowblk) so blocks sharing
// A-rows are adjacent in dispatch order. Pipelined A-loads; no inner barriers.
// LDS frag index: ((gate*2 + j2)*4 + kk) ; gate 0..5 = ih_r,ih_z,ih_n,hh_r,hh_z,hh_n
// ---------------------------------------------------------------------------
__global__ __launch_bounds__(256) void gru_fused(const unsigned short* __restrict__ Agg,
                                                 const unsigned short* __restrict__ Hin,
                                                 unsigned short* __restrict__ Hout,
                                                 const unsigned short* __restrict__ Wih,
                                                 const unsigned short* __restrict__ Whh,
                                                 const float* __restrict__ bih,
                                                 const float* __restrict__ bhh) {
    __shared__ unsigned short lds[48 * 512];   // 48 KB
    const int lane = threadIdx.x & 63, wave = threadIdx.x >> 6;
    const int rl = lane & 15, kg = lane >> 4;
    const int c0 = blockIdx.x * 32;
    for (int q = wave; q < 48; q += 4) {
        int s2 = q >> 2, kk = q & 3;
        int s = s2 >> 1, j2 = s2 & 1;
        const unsigned short* base = (s < 3) ? Wih + (size_t)s * 128 * KD
                                             : Whh + (size_t)(s - 3) * 128 * KD;
        stage_frag(base + (size_t)(c0 + j2 * 16 + rl) * KD + kk * 32 + kg * 8,
                   lds + q * 512);
    }
    __syncthreads();
    float bi_r[2], bi_z[2], bi_n[2], bh_r[2], bh_z[2], bh_n[2];
#pragma unroll
    for (int j2 = 0; j2 < 2; ++j2) {
        int col = c0 + j2 * 16 + rl;
        bi_r[j2] = bih[col]; bi_z[j2] = bih[128 + col]; bi_n[j2] = bih[256 + col];
        bh_r[j2] = bhh[col]; bh_z[j2] = bhh[128 + col]; bh_n[j2] = bhh[256 + col];
    }
    const int stride = gridDim.y << 2;
    int rt = blockIdx.y * 4 + wave;
    if (rt >= RT_TILES) return;
    bf16x8 a1[4], a2[4];
#pragma unroll
    for (int kk = 0; kk < 4; ++kk) {
        a1[kk] = ldfrag(Agg + ((size_t)rt * 16 + rl) * KD + kk * 32 + kg * 8);
        a2[kk] = ldfrag(Hin + ((size_t)rt * 16 + rl) * KD + kk * 32 + kg * 8);
    }
    while (rt < RT_TILES) {
        const int rtn = rt + stride;
        bf16x8 n1[4], n2[4];
        if (rtn < RT_TILES) {
#pragma unroll
            for (int kk = 0; kk < 4; ++kk) {
                n1[kk] = ldfrag(Agg + ((size_t)rtn * 16 + rl) * KD + kk * 32 + kg * 8);
                n2[kk] = ldfrag(Hin + ((size_t)rtn * 16 + rl) * KD + kk * 32 + kg * 8);
            }
        }
#pragma unroll
        for (int j2 = 0; j2 < 2; ++j2) {
            f32x4 ir = {0.f,0.f,0.f,0.f}, iz = ir, in_ = ir, hr = ir, hz = ir, hn = ir;
#pragma unroll
            for (int kk = 0; kk < 4; ++kk) {
                ir  = __builtin_amdgcn_mfma_f32_16x16x32_bf16(a1[kk], ldfrag(lds + ((0*2+j2)*4+kk)*512 + lane*8), ir,  0, 0, 0);
                iz  = __builtin_amdgcn_mfma_f32_16x16x32_bf16(a1[kk], ldfrag(lds + ((1*2+j2)*4+kk)*512 + lane*8), iz,  0, 0, 0);
                in_ = __builtin_amdgcn_mfma_f32_16x16x32_bf16(a1[kk], ldfrag(lds + ((2*2+j2)*4+kk)*512 + lane*8), in_, 0, 0, 0);
                hr  = __builtin_amdgcn_mfma_f32_16x16x32_bf16(a2[kk], ldfrag(lds + ((3*2+j2)*4+kk)*512 + lane*8), hr,  0, 0, 0);
                hz  = __builtin_amdgcn_mfma_f32_16x16x32_bf16(a2[kk], ldfrag(lds + ((4*2+j2)*4+kk)*512 + lane*8), hz,  0, 0, 0);
                hn  = __builtin_amdgcn_mfma_f32_16x16x32_bf16(a2[kk], ldfrag(lds + ((5*2+j2)*4+kk)*512 + lane*8), hn,  0, 0, 0);
            }
            const int col = c0 + j2 * 16 + rl;
#pragma unroll
            for (int p = 0; p < 4; ++p) {
                int row = rt * 16 + kg * 4 + p;
                float r = fsig(ir[p] + bi_r[j2] + hr[p] + bh_r[j2]);
                float z = fsig(iz[p] + bi_z[j2] + hz[p] + bh_z[j2]);
                float nc = ftanh(in_[p] + bi_n[j2] + r * (hn[p] + bh_n[j2]));
                float hv = bf2f(Hin[(size_t)row * KD + col]);
                Hout[(size_t)row * KD + col] = f2bf((1.f - z) * nc + z * hv);
            }
        }
        rt = rtn;
#pragma unroll
        for (int kk = 0; kk < 4; ++kk) { a1[kk] = n1[kk]; a2[kk] = n2[kk]; }
    }
}

// ---------------------------------------------------------------------------
// Fused LSTM, col-split 4: 32 output cols/block, 64 KB weights staged once.
// LDS frag index: ((gate*2 + j2)*4 + kk) ; gate 0..7 = ih_i,f,g,o, hh_i,f,g,o
// ---------------------------------------------------------------------------
__global__ __launch_bounds__(256) void lstm_fused(const unsigned short* __restrict__ Hh,
                                                  const unsigned short* __restrict__ Hx,
                                                  const float* __restrict__ Cx,
                                                  const unsigned short* __restrict__ Wih,
                                                  const unsigned short* __restrict__ Whh,
                                                  const float* __restrict__ bih,
                                                  const float* __restrict__ bhh,
                                                  float* __restrict__ h_out,
                                                  float* __restrict__ c_out,
                                                  unsigned short* __restrict__ Hrelu) {
    __shared__ unsigned short lds[64 * 512];   // 64 KB
    const int lane = threadIdx.x & 63, wave = threadIdx.x >> 6;
    const int rl = lane & 15, kg = lane >> 4;
    const int c0 = blockIdx.x * 32;
    for (int q = wave; q < 64; q += 4) {
        int s2 = q >> 2, kk = q & 3;
        int s = s2 >> 1, j2 = s2 & 1;
        const unsigned short* base = (s < 4) ? Wih + (size_t)s * 128 * KD
                                             : Whh + (size_t)(s - 4) * 128 * KD;
        stage_frag(base + (size_t)(c0 + j2 * 16 + rl) * KD + kk * 32 + kg * 8,
                   lds + q * 512);
    }
    __syncthreads();
    float b_i[2], b_f[2], b_g[2], b_o[2];
#pragma unroll
    for (int j2 = 0; j2 < 2; ++j2) {
        int col = c0 + j2 * 16 + rl;
        b_i[j2] = bih[col] + bhh[col];
        b_f[j2] = bih[128 + col] + bhh[128 + col];
        b_g[j2] = bih[256 + col] + bhh[256 + col];
        b_o[j2] = bih[384 + col] + bhh[384 + col];
    }
    const int stride = gridDim.y << 2;
    int rt = blockIdx.y * 4 + wave;
    if (rt >= RT_TILES) return;
    bf16x8 a1[4], a2[4];
    float cpre[2][4];
#pragma unroll
    for (int kk = 0; kk < 4; ++kk) {
        a1[kk] = ldfrag(Hh + ((size_t)rt * 16 + rl) * KD + kk * 32 + kg * 8);
        a2[kk] = ldfrag(Hx + ((size_t)rt * 16 + rl) * KD + kk * 32 + kg * 8);
    }
#pragma unroll
    for (int j2 = 0; j2 < 2; ++j2)
#pragma unroll
        for (int p = 0; p < 4; ++p)
            cpre[j2][p] = Cx[(size_t)(rt * 16 + kg * 4 + p) * KD + c0 + j2 * 16 + rl];
    while (rt < RT_TILES) {
        const int rtn = rt + stride;
        bf16x8 n1[4], n2[4];
        float cnx[2][4];
        if (rtn < RT_TILES) {
#pragma unroll
            for (int kk = 0; kk < 4; ++kk) {
                n1[kk] = ldfrag(Hh + ((size_t)rtn * 16 + rl) * KD + kk * 32 + kg * 8);
                n2[kk] = ldfrag(Hx + ((size_t)rtn * 16 + rl) * KD + kk * 32 + kg * 8);
            }
#pragma unroll
            for (int j2 = 0; j2 < 2; ++j2)
#pragma unroll
                for (int p = 0; p < 4; ++p)
                    cnx[j2][p] = Cx[(size_t)(rtn * 16 + kg * 4 + p) * KD + c0 + j2 * 16 + rl];
        }
#pragma unroll
        for (int j2 = 0; j2 < 2; ++j2) {
            f32x4 gi = {0.f,0.f,0.f,0.f}, gf = gi, gg = gi, go = gi;
            f32x4 hi = gi, hf = gi, hg = gi, ho = gi;
#pragma unroll
            for (int kk = 0; kk < 4; ++kk) {
                gi = __builtin_amdgcn_mfma_f32_16x16x32_bf16(a1[kk], ldfrag(lds + ((0*2+j2)*4+kk)*512 + lane*8), gi, 0, 0, 0);
                gf = __builtin_amdgcn_mfma_f32_16x16x32_bf16(a1[kk], ldfrag(lds + ((1*2+j2)*4+kk)*512 + lane*8), gf, 0, 0, 0);
                gg = __builtin_amdgcn_mfma_f32_16x16x32_bf16(a1[kk], ldfrag(lds + ((2*2+j2)*4+kk)*512 + lane*8), gg, 0, 0, 0);
                go = __builtin_amdgcn_mfma_f32_16x16x32_bf16(a1[kk], ldfrag(lds + ((3*2+j2)*4+kk)*512 + lane*8), go, 0, 0, 0);
                hi = __builtin_amdgcn_mfma_f32_16x16x32_bf16(a2[kk], ldfrag(lds + ((4*2+j2)*4+kk)*512 + lane*8), hi, 0, 0, 0);
                hf = __builtin_amdgcn_mfma_f32_16x16x32_bf16(a2[kk], ldfrag(lds + ((5*2+j2)*4+kk)*512 + lane*8), hf, 0, 0, 0);
                hg = __builtin_amdgcn_mfma_f32_16x16x32_bf16(a2[kk], ldfrag(lds + ((6*2+j2)*4+kk)*512 + lane*8), hg, 0, 0, 0);
                ho = __builtin_amdgcn_mfma_f32_16x16x32_bf16(a2[kk], ldfrag(lds + ((7*2+j2)*4+kk)*512 + lane*8), ho, 0, 0, 0);
            }
            const int col = c0 + j2 * 16 + rl;
#pragma unroll
            for (int p = 0; p < 4; ++p) {
                int row = rt * 16 + kg * 4 + p;
                size_t idx = (size_t)row * KD + col;
                float ig = fsig(gi[p] + hi[p] + b_i[j2]);
                float fg = fsig(gf[p] + hf[p] + b_f[j2]);
                float gv = ftanh(gg[p] + hg[p] + b_g[j2]);
                float og = fsig(go[p] + ho[p] + b_o[j2]);
                float c = fg * cpre[j2][p] + ig * gv;
                float hn = og * ftanh(c);
                c_out[idx] = c;
                h_out[idx] = hn;
                Hrelu[idx] = f2bf(fmaxf(hn, 0.f));
            }
        }
        rt = rtn;
#pragma unroll
        for (int kk = 0; kk < 4; ++kk) { a1[kk] = n1[kk]; a2[kk] = n2[kk]; }
#pragma unroll
        for (int j2 = 0; j2 < 2; ++j2)
#pragma unroll
            for (int p = 0; p < 4; ++p) cpre[j2][p] = cnx[j2][p];
    }
}

// ---------------------------------------------------------------------------
// head: out[N][64] = hrelu @ lin_wᵀ + lin_b; pipelined row-stride.
// ---------------------------------------------------------------------------
__global__ __launch_bounds__(256) void head_gemm(const unsigned short* __restrict__ Hr,
                                                 const unsigned short* __restrict__ LinW,
                                                 const float* __restrict__ lin_b,
                                                 float* __restrict__ Out) {
    __shared__ unsigned short wlds[16 * 512];
    const int lane = threadIdx.x & 63, wave = threadIdx.x >> 6;
    const int rl = lane & 15, kg = lane >> 4;
    for (int f = wave; f < 16; f += 4) {
        int jt = f >> 2, kk = f & 3;
        stage_frag(LinW + (size_t)(jt * 16 + rl) * KD + kk * 32 + kg * 8, wlds + f * 512);
    }
    __syncthreads();
    const int stride = gridDim.x << 2;
    int rt = blockIdx.x * 4 + wave;
    if (rt >= RT_TILES) return;
    bf16x8 a[4];
#pragma unroll
    for (int kk = 0; kk < 4; ++kk)
        a[kk] = ldfrag(Hr + ((size_t)rt * 16 + rl) * KD + kk * 32 + kg * 8);
    while (rt < RT_TILES) {
        const int rtn = rt + stride;
        bf16x8 an[4];
        if (rtn < RT_TILES) {
#pragma unroll
            for (int kk = 0; kk < 4; ++kk)
                an[kk] = ldfrag(Hr + ((size_t)rtn * 16 + rl) * KD + kk * 32 + kg * 8);
        }
#pragma unroll
        for (int jt = 0; jt < 4; ++jt) {
            f32x4 acc = {0.f, 0.f, 0.f, 0.f};
#pragma unroll
            for (int kk = 0; kk < 4; ++kk)
                acc = __builtin_amdgcn_mfma_f32_16x16x32_bf16(
                    a[kk], ldfrag(wlds + (jt * 4 + kk) * 512 + lane * 8), acc, 0, 0, 0);
            int col = jt * 16 + rl;
            float b = lin_b[col];
#pragma unroll
            for (int p = 0; p < 4; ++p)
                Out[(size_t)(rt * 16 + kg * 4 + p) * 64 + col] = acc[p] + b;
        }
        rt = rtn;
#pragma unroll
        for (int kk = 0; kk < 4; ++kk) a[kk] = an[kk];
    }
}

extern "C" void kernel_launch(void* const* d_in, const int* in_sizes, int n_in,
                              void* d_out, int out_size, void* d_ws, size_t ws_size,
                              hipStream_t stream) {
    const float* x        = (const float*)d_in[0];
    const int*   ei       = (const int*)d_in[1];
    const float* ew       = (const float*)d_in[2];
    const float* H        = (const float*)d_in[3];
    const float* C        = (const float*)d_in[4];
    const float* ggc_w    = (const float*)d_in[5];
    const float* gru_wih  = (const float*)d_in[6];
    const float* gru_whh  = (const float*)d_in[7];
    const float* gru_bih  = (const float*)d_in[8];
    const float* gru_bhh  = (const float*)d_in[9];
    const float* lstm_wih = (const float*)d_in[10];
    const float* lstm_whh = (const float*)d_in[11];
    const float* lstm_bih = (const float*)d_in[12];
    const float* lstm_bhh = (const float*)d_in[13];
    const float* lin_w    = (const float*)d_in[14];
    const float* lin_b    = (const float*)d_in[15];

    float* out_head = (float*)d_out;
    float* h_out = out_head + (size_t)N_NODES * 64;
    float* c_out = h_out + (size_t)N_NODES * KD;

    char* w = (char*)d_ws;
    unsigned short* hb    = (unsigned short*)w; w += (size_t)N_NODES * KD * 2;
    unsigned short* hb1   = (unsigned short*)w; w += (size_t)N_NODES * KD * 2;
    unsigned short* Hxb   = (unsigned short*)w; w += (size_t)N_NODES * KD * 2;
    unsigned short* mb    = (unsigned short*)w; w += (size_t)N_NODES * KD * 2;
    unsigned short* aggb  = (unsigned short*)w; w += (size_t)N_NODES * KD * 2;
    unsigned short* wgTb  = (unsigned short*)w; w += 2 * KD * KD * 2;
    unsigned short* wihb  = (unsigned short*)w; w += 384 * KD * 2;
    unsigned short* whhb  = (unsigned short*)w; w += 384 * KD * 2;
    unsigned short* lwihb = (unsigned short*)w; w += 512 * KD * 2;
    unsigned short* lwhhb = (unsigned short*)w; w += 512 * KD * 2;
    unsigned short* linwb = (unsigned short*)w; w += 64 * KD * 2;
    int*   rowptr = (int*)w; w += 50304 * 4;
    int*   cursor = (int*)w; w += 50304 * 4;
    int*   bsum   = (int*)w; w += 256 * 4;
    int*   sSrc   = (int*)w; w += (size_t)E_EDGES * 4;
    float* sW     = (float*)w; w += (size_t)E_EDGES * 4;

    dim3 blk(256);
    const int EB = (E_EDGES + 255) / 256;
    const int NF4 = N_NODES * KD / 4;
    const dim3 cellGrid(4, 196);   // x = col-group (adjacent IDs share A-rows)

    cvt_xh<<<(2 * NF4 + 255) / 256, blk, 0, stream>>>(x, H, hb, Hxb, NF4);
    cvt_weights<<<(59392 + 255) / 256, blk, 0, stream>>>(
        gru_wih, gru_whh, lstm_wih, lstm_whh, lin_w,
        wihb, whhb, lwihb, lwhhb, linwb);
    transpose_wg_bf16<<<128, blk, 0, stream>>>(ggc_w, wgTb);

    hipMemsetAsync(cursor, 0, N_NODES * sizeof(int), stream);
    count_deg<<<EB, blk, 0, stream>>>(ei, cursor);
    scan_p1<<<NBLK_SCAN, blk, 0, stream>>>(cursor, rowptr, bsum);
    scan_p2<<<1, blk, 0, stream>>>(bsum, rowptr + N_NODES);
    scan_p3<<<NBLK_SCAN, blk, 0, stream>>>(bsum, rowptr, cursor);
    fill_csr<<<EB, blk, 0, stream>>>(ei, ew, cursor, sSrc, sW);

    mfma_gemm_m<<<391, blk, 0, stream>>>(hb, wgTb, mb);
    gather_agg_bf16<<<(N_NODES * 64 + 255) / 256, blk, 0, stream>>>(
        mb, rowptr, sSrc, sW, aggb);
    gru_fused<<<cellGrid, blk, 0, stream>>>(aggb, hb, hb1, wihb, whhb, gru_bih, gru_bhh);

    mfma_gemm_m<<<391, blk, 0, stream>>>(hb1, wgTb + (size_t)KD * KD, mb);
    gather_agg_bf16<<<(N_NODES * 64 + 255) / 256, blk, 0, stream>>>(
        mb, rowptr, sSrc, sW, aggb);
    gru_fused<<<cellGrid, blk, 0, stream>>>(aggb, hb1, hb, wihb, whhb, gru_bih, gru_bhh);

    lstm_fused<<<cellGrid, blk, 0, stream>>>(hb, Hxb, C, lwihb, lwhhb,
                                             lstm_bih, lstm_bhh, h_out, c_out, mb);
    head_gemm<<<391, blk, 0, stream>>>(mb, linwb, lin_b, out_head);
}

// Round 9
// 360.678 us; speedup vs baseline: 1.1106x; 1.1106x over previous
//
#include <hip/hip_runtime.h>
#include <math.h>

#define N_NODES 50000
#define E_EDGES 800000
#define KD 128
#define NBLK_SCAN 196   // ceil(50000/256)
#define RT_TILES 3125   // N_NODES / 16 (exact)

typedef __attribute__((ext_vector_type(8))) short bf16x8;
typedef __attribute__((ext_vector_type(4))) float f32x4;

__device__ __forceinline__ float fsig(float x) { return 1.f / (1.f + __expf(-x)); }
__device__ __forceinline__ float ftanh(float x) { return 1.f - 2.f / (1.f + __expf(2.f * x)); }

__device__ __forceinline__ unsigned short f2bf(float f) {
    unsigned u = __float_as_uint(f);
    return (unsigned short)((u + 0x7FFFu + ((u >> 16) & 1u)) >> 16);
}
__device__ __forceinline__ float bf2f(unsigned short b) {
    return __uint_as_float(((unsigned)b) << 16);
}
__device__ __forceinline__ bf16x8 ldfrag(const unsigned short* p) {
    return *(const bf16x8*)(const void*)p;
}
__device__ __forceinline__ void stage_frag(const unsigned short* g, unsigned short* l) {
    __builtin_amdgcn_global_load_lds(
        (const __attribute__((address_space(1))) unsigned int*)g,
        (__attribute__((address_space(3))) unsigned int*)l, 16, 0, 0);
}

// ---------------------------------------------------------------------------
// fp32 -> bf16 converts
// ---------------------------------------------------------------------------
__global__ __launch_bounds__(256) void cvt_xh(const float* __restrict__ x,
                                              const float* __restrict__ H,
                                              unsigned short* __restrict__ hb,
                                              unsigned short* __restrict__ Hxb, int n4) {
    int t = blockIdx.x * 256 + threadIdx.x;
    const float* in; unsigned short* out; int idx;
    if (t < n4) { in = x; out = hb; idx = t; }
    else if (t < 2 * n4) { in = H; out = Hxb; idx = t - n4; }
    else return;
    float4 v = ((const float4*)in)[idx];
    ushort4 o;
    o.x = f2bf(v.x); o.y = f2bf(v.y); o.z = f2bf(v.z); o.w = f2bf(v.w);
    ((ushort4*)out)[idx] = o;
}

__global__ __launch_bounds__(256) void cvt_weights(
        const float* __restrict__ a, const float* __restrict__ b,
        const float* __restrict__ c, const float* __restrict__ d,
        const float* __restrict__ e,
        unsigned short* __restrict__ oa, unsigned short* __restrict__ ob,
        unsigned short* __restrict__ oc, unsigned short* __restrict__ od,
        unsigned short* __restrict__ oe) {
    int t = blockIdx.x * 256 + threadIdx.x;
    const float* in; unsigned short* out; int idx;
    if      (t < 12288)  { in = a; out = oa; idx = t; }
    else if (t < 24576)  { in = b; out = ob; idx = t - 12288; }
    else if (t < 40960)  { in = c; out = oc; idx = t - 24576; }
    else if (t < 57344)  { in = d; out = od; idx = t - 40960; }
    else if (t < 59392)  { in = e; out = oe; idx = t - 57344; }
    else return;
    float4 v = ((const float4*)in)[idx];
    ushort4 o;
    o.x = f2bf(v.x); o.y = f2bf(v.y); o.z = f2bf(v.z); o.w = f2bf(v.w);
    ((ushort4*)out)[idx] = o;
}

__global__ __launch_bounds__(256) void transpose_wg_bf16(const float* __restrict__ W,
                                                         unsigned short* __restrict__ WT) {
    int t = blockIdx.x * 256 + threadIdx.x;
    int l = t >> 14;
    int r = (t >> 7) & 127;
    int c = t & 127;
    WT[l * 16384 + c * 128 + r] = f2bf(W[l * 16384 + r * 128 + c]);
}

// ---------------------------------------------------------------------------
// CSR build
// ---------------------------------------------------------------------------
__global__ __launch_bounds__(256) void count_deg(const int* __restrict__ ei,
                                                 int* __restrict__ deg) {
    int e = blockIdx.x * 256 + threadIdx.x;
    if (e >= E_EDGES) return;
    atomicAdd(&deg[ei[E_EDGES + e]], 1);
}

__global__ __launch_bounds__(256) void scan_p1(const int* __restrict__ deg,
                                               int* __restrict__ excl,
                                               int* __restrict__ bsum) {
    __shared__ int part[256];
    const int t = threadIdx.x;
    const int i = blockIdx.x * 256 + t;
    int v = (i < N_NODES) ? deg[i] : 0;
    part[t] = v;
    __syncthreads();
#pragma unroll
    for (int off = 1; off < 256; off <<= 1) {
        int u = (t >= off) ? part[t - off] : 0;
        __syncthreads();
        part[t] += u;
        __syncthreads();
    }
    if (i < N_NODES) excl[i] = part[t] - v;
    if (t == 255) bsum[blockIdx.x] = part[255];
}

__global__ __launch_bounds__(256) void scan_p2(int* __restrict__ bsum,
                                               int* __restrict__ rowptrN) {
    __shared__ int part[256];
    const int t = threadIdx.x;
    int v = (t < NBLK_SCAN) ? bsum[t] : 0;
    part[t] = v;
    __syncthreads();
#pragma unroll
    for (int off = 1; off < 256; off <<= 1) {
        int u = (t >= off) ? part[t - off] : 0;
        __syncthreads();
        part[t] += u;
        __syncthreads();
    }
    if (t < NBLK_SCAN) bsum[t] = part[t] - v;
    if (t == 255) *rowptrN = part[255];
}

__global__ __launch_bounds__(256) void scan_p3(const int* __restrict__ bsum,
                                               int* __restrict__ rowptr,
                                               int* __restrict__ cursor) {
    int i = blockIdx.x * 256 + threadIdx.x;
    if (i >= N_NODES) return;
    int r = rowptr[i] + bsum[blockIdx.x];
    rowptr[i] = r;
    cursor[i] = r;
}

__global__ __launch_bounds__(256) void fill_csr(const int* __restrict__ ei,
                                                const float* __restrict__ ew,
                                                int* __restrict__ cursor,
                                                int* __restrict__ sSrc,
                                                float* __restrict__ sW) {
    int e = blockIdx.x * 256 + threadIdx.x;
    if (e >= E_EDGES) return;
    int dst = ei[E_EDGES + e];
    int pos = atomicAdd(&cursor[dst], 1);
    sSrc[pos] = ei[e];
    sW[pos] = ew[e];
}

// ---------------------------------------------------------------------------
// agg[n,:] = sum_e w[e]*m[src[e],:]; one node/wave, index prefetch
// ---------------------------------------------------------------------------
__global__ __launch_bounds__(256) void gather_agg_bf16(const unsigned short* __restrict__ m,
                                                       const int* __restrict__ rowptr,
                                                       const int* __restrict__ sSrc,
                                                       const float* __restrict__ sW,
                                                       unsigned short* __restrict__ agg) {
    int wid = (blockIdx.x * 256 + threadIdx.x) >> 6;
    if (wid >= N_NODES) return;
    int lane = threadIdx.x & 63;
    int half = lane >> 5, li = lane & 31;
    int f0 = li << 2;
    int e0 = rowptr[wid], e1 = rowptr[wid + 1];
    float ax = 0.f, ay = 0.f, az = 0.f, aw = 0.f;
    int e = e0 + half;
    int s_nx = 0; float w_nx = 0.f;
    if (e < e1) { s_nx = sSrc[e]; w_nx = sW[e]; }
    for (; e < e1; e += 2) {
        int s = s_nx; float ww = w_nx;
        int en = e + 2;
        if (en < e1) { s_nx = sSrc[en]; w_nx = sW[en]; }
        ushort4 v = *(const ushort4*)(m + (size_t)s * KD + f0);
        ax += ww * bf2f(v.x); ay += ww * bf2f(v.y);
        az += ww * bf2f(v.z); aw += ww * bf2f(v.w);
    }
    ax += __shfl_xor(ax, 32, 64);
    ay += __shfl_xor(ay, 32, 64);
    az += __shfl_xor(az, 32, 64);
    aw += __shfl_xor(aw, 32, 64);
    if (half == 0) {
        ushort4 o;
        o.x = f2bf(ax); o.y = f2bf(ay); o.z = f2bf(az); o.w = f2bf(aw);
        *(ushort4*)(agg + (size_t)wid * KD + f0) = o;
    }
}

// ---------------------------------------------------------------------------
// m = h @ Wg. Weights staged once; pipelined grid-stride over row tiles.
// ---------------------------------------------------------------------------
__global__ __launch_bounds__(256) void mfma_gemm_m(const unsigned short* __restrict__ A,
                                                   const unsigned short* __restrict__ WT,
                                                   unsigned short* __restrict__ Mout) {
    __shared__ unsigned short wlds[32 * 512];
    const int lane = threadIdx.x & 63, wave = threadIdx.x >> 6;
    const int rl = lane & 15, kg = lane >> 4;
    for (int f = wave; f < 32; f += 4) {
        int jt = f >> 2, kk = f & 3;
        stage_frag(WT + (size_t)(jt * 16 + rl) * KD + kk * 32 + kg * 8, wlds + f * 512);
    }
    __syncthreads();
    const int stride = gridDim.x << 2;
    int rt = blockIdx.x * 4 + wave;
    if (rt >= RT_TILES) return;
    bf16x8 a[4];
#pragma unroll
    for (int kk = 0; kk < 4; ++kk)
        a[kk] = ldfrag(A + ((size_t)rt * 16 + rl) * KD + kk * 32 + kg * 8);
    while (rt < RT_TILES) {
        const int rtn = rt + stride;
        bf16x8 an[4];
        if (rtn < RT_TILES) {
#pragma unroll
            for (int kk = 0; kk < 4; ++kk)
                an[kk] = ldfrag(A + ((size_t)rtn * 16 + rl) * KD + kk * 32 + kg * 8);
        }
#pragma unroll
        for (int jt = 0; jt < 8; ++jt) {
            f32x4 acc = {0.f, 0.f, 0.f, 0.f};
#pragma unroll
            for (int kk = 0; kk < 4; ++kk)
                acc = __builtin_amdgcn_mfma_f32_16x16x32_bf16(
                    a[kk], ldfrag(wlds + (jt * 4 + kk) * 512 + lane * 8), acc, 0, 0, 0);
            int col = jt * 16 + rl;
#pragma unroll
            for (int p = 0; p < 4; ++p)
                Mout[(size_t)(rt * 16 + kg * 4 + p) * KD + col] = f2bf(acc[p]);
        }
        rt = rtn;
#pragma unroll
        for (int kk = 0; kk < 4; ++kk) a[kk] = an[kk];
    }
}

// ---------------------------------------------------------------------------
// Fused GRU, col-split 8, grid(x=colgrp, y=rowblk): the 8 blocks sharing
// A-rows are ADJACENT linear block IDs -> L2/L3 reuse. Pipelined A-loads.
// ---------------------------------------------------------------------------
__global__ __launch_bounds__(256) void gru_fused(const unsigned short* __restrict__ Agg,
                                                 const unsigned short* __restrict__ Hin,
                                                 unsigned short* __restrict__ Hout,
                                                 const unsigned short* __restrict__ Wih,
                                                 const unsigned short* __restrict__ Whh,
                                                 const float* __restrict__ bih,
                                                 const float* __restrict__ bhh) {
    __shared__ unsigned short lds[24 * 512];   // 24 KB
    const int lane = threadIdx.x & 63, wave = threadIdx.x >> 6;
    const int rl = lane & 15, kg = lane >> 4;
    const int col0 = blockIdx.x * 16;
    for (int q = wave; q < 24; q += 4) {
        int s = q >> 2, kk = q & 3;
        const unsigned short* src = (s < 3 ? Wih + (size_t)s * 128 * KD
                                           : Whh + (size_t)(s - 3) * 128 * KD)
                                    + (size_t)(col0 + rl) * KD + kk * 32 + kg * 8;
        stage_frag(src, lds + q * 512);
    }
    __syncthreads();
    const int col = col0 + rl;
    const float b_ir = bih[col], b_iz = bih[128 + col], b_in = bih[256 + col];
    const float b_hr = bhh[col], b_hz = bhh[128 + col], b_hn = bhh[256 + col];
    const int stride = gridDim.y << 2;
    int rt = blockIdx.y * 4 + wave;
    if (rt >= RT_TILES) return;
    bf16x8 a1[4], a2[4];
#pragma unroll
    for (int kk = 0; kk < 4; ++kk) {
        a1[kk] = ldfrag(Agg + ((size_t)rt * 16 + rl) * KD + kk * 32 + kg * 8);
        a2[kk] = ldfrag(Hin + ((size_t)rt * 16 + rl) * KD + kk * 32 + kg * 8);
    }
    while (rt < RT_TILES) {
        const int rtn = rt + stride;
        bf16x8 n1[4], n2[4];
        if (rtn < RT_TILES) {
#pragma unroll
            for (int kk = 0; kk < 4; ++kk) {
                n1[kk] = ldfrag(Agg + ((size_t)rtn * 16 + rl) * KD + kk * 32 + kg * 8);
                n2[kk] = ldfrag(Hin + ((size_t)rtn * 16 + rl) * KD + kk * 32 + kg * 8);
            }
        }
        f32x4 ir = {0.f,0.f,0.f,0.f}, iz = ir, in_ = ir, hr = ir, hz = ir, hn = ir;
#pragma unroll
        for (int kk = 0; kk < 4; ++kk) {
            ir  = __builtin_amdgcn_mfma_f32_16x16x32_bf16(a1[kk], ldfrag(lds + (0*4+kk)*512 + lane*8), ir,  0, 0, 0);
            iz  = __builtin_amdgcn_mfma_f32_16x16x32_bf16(a1[kk], ldfrag(lds + (1*4+kk)*512 + lane*8), iz,  0, 0, 0);
            in_ = __builtin_amdgcn_mfma_f32_16x16x32_bf16(a1[kk], ldfrag(lds + (2*4+kk)*512 + lane*8), in_, 0, 0, 0);
            hr  = __builtin_amdgcn_mfma_f32_16x16x32_bf16(a2[kk], ldfrag(lds + (3*4+kk)*512 + lane*8), hr,  0, 0, 0);
            hz  = __builtin_amdgcn_mfma_f32_16x16x32_bf16(a2[kk], ldfrag(lds + (4*4+kk)*512 + lane*8), hz,  0, 0, 0);
            hn  = __builtin_amdgcn_mfma_f32_16x16x32_bf16(a2[kk], ldfrag(lds + (5*4+kk)*512 + lane*8), hn,  0, 0, 0);
        }
#pragma unroll
        for (int p = 0; p < 4; ++p) {
            int row = rt * 16 + kg * 4 + p;
            float r = fsig(ir[p] + b_ir + hr[p] + b_hr);
            float z = fsig(iz[p] + b_iz + hz[p] + b_hz);
            float nc = ftanh(in_[p] + b_in + r * (hn[p] + b_hn));
            float hv = bf2f(Hin[(size_t)row * KD + col]);
            Hout[(size_t)row * KD + col] = f2bf((1.f - z) * nc + z * hv);
        }
        rt = rtn;
#pragma unroll
        for (int kk = 0; kk < 4; ++kk) { a1[kk] = n1[kk]; a2[kk] = n2[kk]; }
    }
}

// ---------------------------------------------------------------------------
// Fused LSTM, col-split 8, grid(x=colgrp, y=rowblk); pipelined A/Cx loads.
// ---------------------------------------------------------------------------
__global__ __launch_bounds__(256) void lstm_fused(const unsigned short* __restrict__ Hh,
                                                  const unsigned short* __restrict__ Hx,
                                                  const float* __restrict__ Cx,
                                                  const unsigned short* __restrict__ Wih,
                                                  const unsigned short* __restrict__ Whh,
                                                  const float* __restrict__ bih,
                                                  const float* __restrict__ bhh,
                                                  float* __restrict__ h_out,
                                                  float* __restrict__ c_out,
                                                  unsigned short* __restrict__ Hrelu) {
    __shared__ unsigned short lds[32 * 512];   // 32 KB
    const int lane = threadIdx.x & 63, wave = threadIdx.x >> 6;
    const int rl = lane & 15, kg = lane >> 4;
    const int col0 = blockIdx.x * 16;
    for (int q = wave; q < 32; q += 4) {
        int s = q >> 2, kk = q & 3;
        const unsigned short* src = (s < 4 ? Wih + (size_t)s * 128 * KD
                                           : Whh + (size_t)(s - 4) * 128 * KD)
                                    + (size_t)(col0 + rl) * KD + kk * 32 + kg * 8;
        stage_frag(src, lds + q * 512);
    }
    __syncthreads();
    const int col = col0 + rl;
    const float b_i = bih[col] + bhh[col];
    const float b_f = bih[128 + col] + bhh[128 + col];
    const float b_g = bih[256 + col] + bhh[256 + col];
    const float b_o = bih[384 + col] + bhh[384 + col];
    const int stride = gridDim.y << 2;
    int rt = blockIdx.y * 4 + wave;
    if (rt >= RT_TILES) return;
    bf16x8 a1[4], a2[4];
    float cpre[4];
#pragma unroll
    for (int kk = 0; kk < 4; ++kk) {
        a1[kk] = ldfrag(Hh + ((size_t)rt * 16 + rl) * KD + kk * 32 + kg * 8);
        a2[kk] = ldfrag(Hx + ((size_t)rt * 16 + rl) * KD + kk * 32 + kg * 8);
    }
#pragma unroll
    for (int p = 0; p < 4; ++p)
        cpre[p] = Cx[(size_t)(rt * 16 + kg * 4 + p) * KD + col];
    while (rt < RT_TILES) {
        const int rtn = rt + stride;
        bf16x8 n1[4], n2[4];
        float cnx[4];
        if (rtn < RT_TILES) {
#pragma unroll
            for (int kk = 0; kk < 4; ++kk) {
                n1[kk] = ldfrag(Hh + ((size_t)rtn * 16 + rl) * KD + kk * 32 + kg * 8);
                n2[kk] = ldfrag(Hx + ((size_t)rtn * 16 + rl) * KD + kk * 32 + kg * 8);
            }
#pragma unroll
            for (int p = 0; p < 4; ++p)
                cnx[p] = Cx[(size_t)(rtn * 16 + kg * 4 + p) * KD + col];
        }
        f32x4 gi = {0.f,0.f,0.f,0.f}, gf = gi, gg = gi, go = gi;
        f32x4 hi = gi, hf = gi, hg = gi, ho = gi;
#pragma unroll
        for (int kk = 0; kk < 4; ++kk) {
            gi = __builtin_amdgcn_mfma_f32_16x16x32_bf16(a1[kk], ldfrag(lds + (0*4+kk)*512 + lane*8), gi, 0, 0, 0);
            gf = __builtin_amdgcn_mfma_f32_16x16x32_bf16(a1[kk], ldfrag(lds + (1*4+kk)*512 + lane*8), gf, 0, 0, 0);
            gg = __builtin_amdgcn_mfma_f32_16x16x32_bf16(a1[kk], ldfrag(lds + (2*4+kk)*512 + lane*8), gg, 0, 0, 0);
            go = __builtin_amdgcn_mfma_f32_16x16x32_bf16(a1[kk], ldfrag(lds + (3*4+kk)*512 + lane*8), go, 0, 0, 0);
            hi = __builtin_amdgcn_mfma_f32_16x16x32_bf16(a2[kk], ldfrag(lds + (4*4+kk)*512 + lane*8), hi, 0, 0, 0);
            hf = __builtin_amdgcn_mfma_f32_16x16x32_bf16(a2[kk], ldfrag(lds + (5*4+kk)*512 + lane*8), hf, 0, 0, 0);
            hg = __builtin_amdgcn_mfma_f32_16x16x32_bf16(a2[kk], ldfrag(lds + (6*4+kk)*512 + lane*8), hg, 0, 0, 0);
            ho = __builtin_amdgcn_mfma_f32_16x16x32_bf16(a2[kk], ldfrag(lds + (7*4+kk)*512 + lane*8), ho, 0, 0, 0);
        }
#pragma unroll
        for (int p = 0; p < 4; ++p) {
            int row = rt * 16 + kg * 4 + p;
            size_t idx = (size_t)row * KD + col;
            float ig = fsig(gi[p] + hi[p] + b_i);
            float fg = fsig(gf[p] + hf[p] + b_f);
            float gv = ftanh(gg[p] + hg[p] + b_g);
            float og = fsig(go[p] + ho[p] + b_o);
            float c = fg * cpre[p] + ig * gv;
            float hn = og * ftanh(c);
            c_out[idx] = c;
            h_out[idx] = hn;
            Hrelu[idx] = f2bf(fmaxf(hn, 0.f));
        }
        rt = rtn;
#pragma unroll
        for (int kk = 0; kk < 4; ++kk) { a1[kk] = n1[kk]; a2[kk] = n2[kk]; }
#pragma unroll
        for (int p = 0; p < 4; ++p) cpre[p] = cnx[p];
    }
}

// ---------------------------------------------------------------------------
// head: out[N][64] = hrelu @ lin_wᵀ + lin_b; pipelined row-stride.
// ---------------------------------------------------------------------------
__global__ __launch_bounds__(256) void head_gemm(const unsigned short* __restrict__ Hr,
                                                 const unsigned short* __restrict__ LinW,
                                                 const float* __restrict__ lin_b,
                                                 float* __restrict__ Out) {
    __shared__ unsigned short wlds[16 * 512];
    const int lane = threadIdx.x & 63, wave = threadIdx.x >> 6;
    const int rl = lane & 15, kg = lane >> 4;
    for (int f = wave; f < 16; f += 4) {
        int jt = f >> 2, kk = f & 3;
        stage_frag(LinW + (size_t)(jt * 16 + rl) * KD + kk * 32 + kg * 8, wlds + f * 512);
    }
    __syncthreads();
    const int stride = gridDim.x << 2;
    int rt = blockIdx.x * 4 + wave;
    if (rt >= RT_TILES) return;
    bf16x8 a[4];
#pragma unroll
    for (int kk = 0; kk < 4; ++kk)
        a[kk] = ldfrag(Hr + ((size_t)rt * 16 + rl) * KD + kk * 32 + kg * 8);
    while (rt < RT_TILES) {
        const int rtn = rt + stride;
        bf16x8 an[4];
        if (rtn < RT_TILES) {
#pragma unroll
            for (int kk = 0; kk < 4; ++kk)
                an[kk] = ldfrag(Hr + ((size_t)rtn * 16 + rl) * KD + kk * 32 + kg * 8);
        }
#pragma unroll
        for (int jt = 0; jt < 4; ++jt) {
            f32x4 acc = {0.f, 0.f, 0.f, 0.f};
#pragma unroll
            for (int kk = 0; kk < 4; ++kk)
                acc = __builtin_amdgcn_mfma_f32_16x16x32_bf16(
                    a[kk], ldfrag(wlds + (jt * 4 + kk) * 512 + lane * 8), acc, 0, 0, 0);
            int col = jt * 16 + rl;
            float b = lin_b[col];
#pragma unroll
            for (int p = 0; p < 4; ++p)
                Out[(size_t)(rt * 16 + kg * 4 + p) * 64 + col] = acc[p] + b;
        }
        rt = rtn;
#pragma unroll
        for (int kk = 0; kk < 4; ++kk) a[kk] = an[kk];
    }
}

extern "C" void kernel_launch(void* const* d_in, const int* in_sizes, int n_in,
                              void* d_out, int out_size, void* d_ws, size_t ws_size,
                              hipStream_t stream) {
    const float* x        = (const float*)d_in[0];
    const int*   ei       = (const int*)d_in[1];
    const float* ew       = (const float*)d_in[2];
    const float* H        = (const float*)d_in[3];
    const float* C        = (const float*)d_in[4];
    const float* ggc_w    = (const float*)d_in[5];
    const float* gru_wih  = (const float*)d_in[6];
    const float* gru_whh  = (const float*)d_in[7];
    const float* gru_bih  = (const float*)d_in[8];
    const float* gru_bhh  = (const float*)d_in[9];
    const float* lstm_wih = (const float*)d_in[10];
    const float* lstm_whh = (const float*)d_in[11];
    const float* lstm_bih = (const float*)d_in[12];
    const float* lstm_bhh = (const float*)d_in[13];
    const float* lin_w    = (const float*)d_in[14];
    const float* lin_b    = (const float*)d_in[15];

    float* out_head = (float*)d_out;
    float* h_out = out_head + (size_t)N_NODES * 64;
    float* c_out = h_out + (size_t)N_NODES * KD;

    char* w = (char*)d_ws;
    unsigned short* hb    = (unsigned short*)w; w += (size_t)N_NODES * KD * 2;
    unsigned short* hb1   = (unsigned short*)w; w += (size_t)N_NODES * KD * 2;
    unsigned short* Hxb   = (unsigned short*)w; w += (size_t)N_NODES * KD * 2;
    unsigned short* mb    = (unsigned short*)w; w += (size_t)N_NODES * KD * 2;
    unsigned short* aggb  = (unsigned short*)w; w += (size_t)N_NODES * KD * 2;
    unsigned short* wgTb  = (unsigned short*)w; w += 2 * KD * KD * 2;
    unsigned short* wihb  = (unsigned short*)w; w += 384 * KD * 2;
    unsigned short* whhb  = (unsigned short*)w; w += 384 * KD * 2;
    unsigned short* lwihb = (unsigned short*)w; w += 512 * KD * 2;
    unsigned short* lwhhb = (unsigned short*)w; w += 512 * KD * 2;
    unsigned short* linwb = (unsigned short*)w; w += 64 * KD * 2;
    int*   rowptr = (int*)w; w += 50304 * 4;
    int*   cursor = (int*)w; w += 50304 * 4;
    int*   bsum   = (int*)w; w += 256 * 4;
    int*   sSrc   = (int*)w; w += (size_t)E_EDGES * 4;
    float* sW     = (float*)w; w += (size_t)E_EDGES * 4;

    dim3 blk(256);
    const int EB = (E_EDGES + 255) / 256;
    const int NF4 = N_NODES * KD / 4;
    const dim3 cellGrid(8, 196);   // x = colgroup: row-sharers are ADJACENT IDs

    cvt_xh<<<(2 * NF4 + 255) / 256, blk, 0, stream>>>(x, H, hb, Hxb, NF4);
    cvt_weights<<<(59392 + 255) / 256, blk, 0, stream>>>(
        gru_wih, gru_whh, lstm_wih, lstm_whh, lin_w,
        wihb, whhb, lwihb, lwhhb, linwb);
    transpose_wg_bf16<<<128, blk, 0, stream>>>(ggc_w, wgTb);

    hipMemsetAsync(cursor, 0, N_NODES * sizeof(int), stream);
    count_deg<<<EB, blk, 0, stream>>>(ei, cursor);
    scan_p1<<<NBLK_SCAN, blk, 0, stream>>>(cursor, rowptr, bsum);
    scan_p2<<<1, blk, 0, stream>>>(bsum, rowptr + N_NODES);
    scan_p3<<<NBLK_SCAN, blk, 0, stream>>>(bsum, rowptr, cursor);
    fill_csr<<<EB, blk, 0, stream>>>(ei, ew, cursor, sSrc, sW);

    mfma_gemm_m<<<391, blk, 0, stream>>>(hb, wgTb, mb);
    gather_agg_bf16<<<(N_NODES * 64 + 255) / 256, blk, 0, stream>>>(
        mb, rowptr, sSrc, sW, aggb);
    gru_fused<<<cellGrid, blk, 0, stream>>>(aggb, hb, hb1, wihb, whhb, gru_bih, gru_bhh);

    mfma_gemm_m<<<391, blk, 0, stream>>>(hb1, wgTb + (size_t)KD * KD, mb);
    gather_agg_bf16<<<(N_NODES * 64 + 255) / 256, blk, 0, stream>>>(
        mb, rowptr, sSrc, sW, aggb);
    gru_fused<<<cellGrid, blk, 0, stream>>>(aggb, hb1, hb, wihb, whhb, gru_bih, gru_bhh);

    lstm_fused<<<cellGrid, blk, 0, stream>>>(hb, Hxb, C, lwihb, lwhhb,
                                             lstm_bih, lstm_bhh, h_out, c_out, mb);
    head_gemm<<<391, blk, 0, stream>>>(mb, linwb, lin_b, out_head);
}

// Round 10
// 352.026 us; speedup vs baseline: 1.1379x; 1.0246x over previous
//
#include <hip/hip_runtime.h>
#include <math.h>

#define N_NODES 50000
#define E_EDGES 800000
#define KD 128
#define NBLK_SCAN 196   // ceil(50000/256)
#define RT_TILES 3125   // N_NODES / 16 (exact)
#define CELL_RB 196     // rowblocks in cell kernels
#define CELL_STRIDE (CELL_RB * 4)

typedef __attribute__((ext_vector_type(8))) short bf16x8;
typedef __attribute__((ext_vector_type(4))) float f32x4;

__device__ __forceinline__ float fsig(float x) { return 1.f / (1.f + __expf(-x)); }
__device__ __forceinline__ float ftanh(float x) { return 1.f - 2.f / (1.f + __expf(2.f * x)); }

__device__ __forceinline__ unsigned short f2bf(float f) {
    unsigned u = __float_as_uint(f);
    return (unsigned short)((u + 0x7FFFu + ((u >> 16) & 1u)) >> 16);
}
__device__ __forceinline__ float bf2f(unsigned short b) {
    return __uint_as_float(((unsigned)b) << 16);
}
__device__ __forceinline__ bf16x8 ldfrag(const unsigned short* p) {
    return *(const bf16x8*)(const void*)p;
}
__device__ __forceinline__ void stage_frag(const unsigned short* g, unsigned short* l) {
    __builtin_amdgcn_global_load_lds(
        (const __attribute__((address_space(1))) unsigned int*)g,
        (__attribute__((address_space(3))) unsigned int*)l, 16, 0, 0);
}
// XCD-aware decode: 8 colgroup-sharers of a rowblock get ids spaced 8 apart
// (same id%8 -> same XCD, co-resident) ; consecutive rowblocks rotate XCDs.
__device__ __forceinline__ void cell_decode(int id, int& x, int& y) {
    y = ((id >> 6) << 3) + (id & 7);   // rowblock 0..199 (>=196 invalid)
    x = (id >> 3) & 7;                 // colgroup 0..7
}

// ---------------------------------------------------------------------------
// fp32 -> bf16 converts
// ---------------------------------------------------------------------------
__global__ __launch_bounds__(256) void cvt_xh(const float* __restrict__ x,
                                              const float* __restrict__ H,
                                              unsigned short* __restrict__ hb,
                                              unsigned short* __restrict__ Hxb, int n4) {
    int t = blockIdx.x * 256 + threadIdx.x;
    const float* in; unsigned short* out; int idx;
    if (t < n4) { in = x; out = hb; idx = t; }
    else if (t < 2 * n4) { in = H; out = Hxb; idx = t - n4; }
    else return;
    float4 v = ((const float4*)in)[idx];
    ushort4 o;
    o.x = f2bf(v.x); o.y = f2bf(v.y); o.z = f2bf(v.z); o.w = f2bf(v.w);
    ((ushort4*)out)[idx] = o;
}

__global__ __launch_bounds__(256) void cvt_weights(
        const float* __restrict__ a, const float* __restrict__ b,
        const float* __restrict__ c, const float* __restrict__ d,
        const float* __restrict__ e,
        unsigned short* __restrict__ oa, unsigned short* __restrict__ ob,
        unsigned short* __restrict__ oc, unsigned short* __restrict__ od,
        unsigned short* __restrict__ oe) {
    int t = blockIdx.x * 256 + threadIdx.x;
    const float* in; unsigned short* out; int idx;
    if      (t < 12288)  { in = a; out = oa; idx = t; }
    else if (t < 24576)  { in = b; out = ob; idx = t - 12288; }
    else if (t < 40960)  { in = c; out = oc; idx = t - 24576; }
    else if (t < 57344)  { in = d; out = od; idx = t - 40960; }
    else if (t < 59392)  { in = e; out = oe; idx = t - 57344; }
    else return;
    float4 v = ((const float4*)in)[idx];
    ushort4 o;
    o.x = f2bf(v.x); o.y = f2bf(v.y); o.z = f2bf(v.z); o.w = f2bf(v.w);
    ((ushort4*)out)[idx] = o;
}

__global__ __launch_bounds__(256) void transpose_wg_bf16(const float* __restrict__ W,
                                                         unsigned short* __restrict__ WT) {
    int t = blockIdx.x * 256 + threadIdx.x;
    int l = t >> 14;
    int r = (t >> 7) & 127;
    int c = t & 127;
    WT[l * 16384 + c * 128 + r] = f2bf(W[l * 16384 + r * 128 + c]);
}

// ---------------------------------------------------------------------------
// CSR build
// ---------------------------------------------------------------------------
__global__ __launch_bounds__(256) void count_deg(const int* __restrict__ ei,
                                                 int* __restrict__ deg) {
    int e = blockIdx.x * 256 + threadIdx.x;
    if (e >= E_EDGES) return;
    atomicAdd(&deg[ei[E_EDGES + e]], 1);
}

__global__ __launch_bounds__(256) void scan_p1(const int* __restrict__ deg,
                                               int* __restrict__ excl,
                                               int* __restrict__ bsum) {
    __shared__ int part[256];
    const int t = threadIdx.x;
    const int i = blockIdx.x * 256 + t;
    int v = (i < N_NODES) ? deg[i] : 0;
    part[t] = v;
    __syncthreads();
#pragma unroll
    for (int off = 1; off < 256; off <<= 1) {
        int u = (t >= off) ? part[t - off] : 0;
        __syncthreads();
        part[t] += u;
        __syncthreads();
    }
    if (i < N_NODES) excl[i] = part[t] - v;
    if (t == 255) bsum[blockIdx.x] = part[255];
}

__global__ __launch_bounds__(256) void scan_p2(int* __restrict__ bsum,
                                               int* __restrict__ rowptrN) {
    __shared__ int part[256];
    const int t = threadIdx.x;
    int v = (t < NBLK_SCAN) ? bsum[t] : 0;
    part[t] = v;
    __syncthreads();
#pragma unroll
    for (int off = 1; off < 256; off <<= 1) {
        int u = (t >= off) ? part[t - off] : 0;
        __syncthreads();
        part[t] += u;
        __syncthreads();
    }
    if (t < NBLK_SCAN) bsum[t] = part[t] - v;
    if (t == 255) *rowptrN = part[255];
}

__global__ __launch_bounds__(256) void scan_p3(const int* __restrict__ bsum,
                                               int* __restrict__ rowptr,
                                               int* __restrict__ cursor) {
    int i = blockIdx.x * 256 + threadIdx.x;
    if (i >= N_NODES) return;
    int r = rowptr[i] + bsum[blockIdx.x];
    rowptr[i] = r;
    cursor[i] = r;
}

__global__ __launch_bounds__(256) void fill_csr(const int* __restrict__ ei,
                                                const float* __restrict__ ew,
                                                int* __restrict__ cursor,
                                                int* __restrict__ sSrc,
                                                float* __restrict__ sW) {
    int e = blockIdx.x * 256 + threadIdx.x;
    if (e >= E_EDGES) return;
    int dst = ei[E_EDGES + e];
    int pos = atomicAdd(&cursor[dst], 1);
    sSrc[pos] = ei[e];
    sW[pos] = ew[e];
}

// ---------------------------------------------------------------------------
// agg[n,:] = sum_e w[e]*m[src[e],:]; one node/wave, index prefetch
// ---------------------------------------------------------------------------
__global__ __launch_bounds__(256) void gather_agg_bf16(const unsigned short* __restrict__ m,
                                                       const int* __restrict__ rowptr,
                                                       const int* __restrict__ sSrc,
                                                       const float* __restrict__ sW,
                                                       unsigned short* __restrict__ agg) {
    int wid = (blockIdx.x * 256 + threadIdx.x) >> 6;
    if (wid >= N_NODES) return;
    int lane = threadIdx.x & 63;
    int half = lane >> 5, li = lane & 31;
    int f0 = li << 2;
    int e0 = rowptr[wid], e1 = rowptr[wid + 1];
    float ax = 0.f, ay = 0.f, az = 0.f, aw = 0.f;
    int e = e0 + half;
    int s_nx = 0; float w_nx = 0.f;
    if (e < e1) { s_nx = sSrc[e]; w_nx = sW[e]; }
    for (; e < e1; e += 2) {
        int s = s_nx; float ww = w_nx;
        int en = e + 2;
        if (en < e1) { s_nx = sSrc[en]; w_nx = sW[en]; }
        ushort4 v = *(const ushort4*)(m + (size_t)s * KD + f0);
        ax += ww * bf2f(v.x); ay += ww * bf2f(v.y);
        az += ww * bf2f(v.z); aw += ww * bf2f(v.w);
    }
    ax += __shfl_xor(ax, 32, 64);
    ay += __shfl_xor(ay, 32, 64);
    az += __shfl_xor(az, 32, 64);
    aw += __shfl_xor(aw, 32, 64);
    if (half == 0) {
        ushort4 o;
        o.x = f2bf(ax); o.y = f2bf(ay); o.z = f2bf(az); o.w = f2bf(aw);
        *(ushort4*)(agg + (size_t)wid * KD + f0) = o;
    }
}

// ---------------------------------------------------------------------------
// m = h @ Wg. Weights staged once; pipelined grid-stride over row tiles.
// ---------------------------------------------------------------------------
__global__ __launch_bounds__(256) void mfma_gemm_m(const unsigned short* __restrict__ A,
                                                   const unsigned short* __restrict__ WT,
                                                   unsigned short* __restrict__ Mout) {
    __shared__ unsigned short wlds[32 * 512];
    const int lane = threadIdx.x & 63, wave = threadIdx.x >> 6;
    const int rl = lane & 15, kg = lane >> 4;
    for (int f = wave; f < 32; f += 4) {
        int jt = f >> 2, kk = f & 3;
        stage_frag(WT + (size_t)(jt * 16 + rl) * KD + kk * 32 + kg * 8, wlds + f * 512);
    }
    __syncthreads();
    const int stride = gridDim.x << 2;
    int rt = blockIdx.x * 4 + wave;
    if (rt >= RT_TILES) return;
    bf16x8 a[4];
#pragma unroll
    for (int kk = 0; kk < 4; ++kk)
        a[kk] = ldfrag(A + ((size_t)rt * 16 + rl) * KD + kk * 32 + kg * 8);
    while (rt < RT_TILES) {
        const int rtn = rt + stride;
        bf16x8 an[4];
        if (rtn < RT_TILES) {
#pragma unroll
            for (int kk = 0; kk < 4; ++kk)
                an[kk] = ldfrag(A + ((size_t)rtn * 16 + rl) * KD + kk * 32 + kg * 8);
        }
#pragma unroll
        for (int jt = 0; jt < 8; ++jt) {
            f32x4 acc = {0.f, 0.f, 0.f, 0.f};
#pragma unroll
            for (int kk = 0; kk < 4; ++kk)
                acc = __builtin_amdgcn_mfma_f32_16x16x32_bf16(
                    a[kk], ldfrag(wlds + (jt * 4 + kk) * 512 + lane * 8), acc, 0, 0, 0);
            int col = jt * 16 + rl;
#pragma unroll
            for (int p = 0; p < 4; ++p)
                Mout[(size_t)(rt * 16 + kg * 4 + p) * KD + col] = f2bf(acc[p]);
        }
        rt = rtn;
#pragma unroll
        for (int kk = 0; kk < 4; ++kk) a[kk] = an[kk];
    }
}

// ---------------------------------------------------------------------------
// Fused GRU, col-split 8, XCD-aware block mapping (sharers co-resident on
// one XCD's L2). Pipelined A-loads; no inner barriers.
// ---------------------------------------------------------------------------
__global__ __launch_bounds__(256) void gru_fused(const unsigned short* __restrict__ Agg,
                                                 const unsigned short* __restrict__ Hin,
                                                 unsigned short* __restrict__ Hout,
                                                 const unsigned short* __restrict__ Wih,
                                                 const unsigned short* __restrict__ Whh,
                                                 const float* __restrict__ bih,
                                                 const float* __restrict__ bhh) {
    int cg, rb;
    cell_decode(blockIdx.x, cg, rb);
    if (rb >= CELL_RB) return;
    __shared__ unsigned short lds[24 * 512];   // 24 KB
    const int lane = threadIdx.x & 63, wave = threadIdx.x >> 6;
    const int rl = lane & 15, kg = lane >> 4;
    const int col0 = cg * 16;
    for (int q = wave; q < 24; q += 4) {
        int s = q >> 2, kk = q & 3;
        const unsigned short* src = (s < 3 ? Wih + (size_t)s * 128 * KD
                                           : Whh + (size_t)(s - 3) * 128 * KD)
                                    + (size_t)(col0 + rl) * KD + kk * 32 + kg * 8;
        stage_frag(src, lds + q * 512);
    }
    __syncthreads();
    const int col = col0 + rl;
    const float b_ir = bih[col], b_iz = bih[128 + col], b_in = bih[256 + col];
    const float b_hr = bhh[col], b_hz = bhh[128 + col], b_hn = bhh[256 + col];
    int rt = rb * 4 + wave;
    if (rt >= RT_TILES) return;
    bf16x8 a1[4], a2[4];
#pragma unroll
    for (int kk = 0; kk < 4; ++kk) {
        a1[kk] = ldfrag(Agg + ((size_t)rt * 16 + rl) * KD + kk * 32 + kg * 8);
        a2[kk] = ldfrag(Hin + ((size_t)rt * 16 + rl) * KD + kk * 32 + kg * 8);
    }
    while (rt < RT_TILES) {
        const int rtn = rt + CELL_STRIDE;
        bf16x8 n1[4], n2[4];
        if (rtn < RT_TILES) {
#pragma unroll
            for (int kk = 0; kk < 4; ++kk) {
                n1[kk] = ldfrag(Agg + ((size_t)rtn * 16 + rl) * KD + kk * 32 + kg * 8);
                n2[kk] = ldfrag(Hin + ((size_t)rtn * 16 + rl) * KD + kk * 32 + kg * 8);
            }
        }
        f32x4 ir = {0.f,0.f,0.f,0.f}, iz = ir, in_ = ir, hr = ir, hz = ir, hn = ir;
#pragma unroll
        for (int kk = 0; kk < 4; ++kk) {
            ir  = __builtin_amdgcn_mfma_f32_16x16x32_bf16(a1[kk], ldfrag(lds + (0*4+kk)*512 + lane*8), ir,  0, 0, 0);
            iz  = __builtin_amdgcn_mfma_f32_16x16x32_bf16(a1[kk], ldfrag(lds + (1*4+kk)*512 + lane*8), iz,  0, 0, 0);
            in_ = __builtin_amdgcn_mfma_f32_16x16x32_bf16(a1[kk], ldfrag(lds + (2*4+kk)*512 + lane*8), in_, 0, 0, 0);
            hr  = __builtin_amdgcn_mfma_f32_16x16x32_bf16(a2[kk], ldfrag(lds + (3*4+kk)*512 + lane*8), hr,  0, 0, 0);
            hz  = __builtin_amdgcn_mfma_f32_16x16x32_bf16(a2[kk], ldfrag(lds + (4*4+kk)*512 + lane*8), hz,  0, 0, 0);
            hn  = __builtin_amdgcn_mfma_f32_16x16x32_bf16(a2[kk], ldfrag(lds + (5*4+kk)*512 + lane*8), hn,  0, 0, 0);
        }
#pragma unroll
        for (int p = 0; p < 4; ++p) {
            int row = rt * 16 + kg * 4 + p;
            float r = fsig(ir[p] + b_ir + hr[p] + b_hr);
            float z = fsig(iz[p] + b_iz + hz[p] + b_hz);
            float nc = ftanh(in_[p] + b_in + r * (hn[p] + b_hn));
            float hv = bf2f(Hin[(size_t)row * KD + col]);
            Hout[(size_t)row * KD + col] = f2bf((1.f - z) * nc + z * hv);
        }
        rt = rtn;
#pragma unroll
        for (int kk = 0; kk < 4; ++kk) { a1[kk] = n1[kk]; a2[kk] = n2[kk]; }
    }
}

// ---------------------------------------------------------------------------
// Fused LSTM, col-split 8, XCD-aware block mapping; pipelined A/Cx loads.
// ---------------------------------------------------------------------------
__global__ __launch_bounds__(256) void lstm_fused(const unsigned short* __restrict__ Hh,
                                                  const unsigned short* __restrict__ Hx,
                                                  const float* __restrict__ Cx,
                                                  const unsigned short* __restrict__ Wih,
                                                  const unsigned short* __restrict__ Whh,
                                                  const float* __restrict__ bih,
                                                  const float* __restrict__ bhh,
                                                  float* __restrict__ h_out,
                                                  float* __restrict__ c_out,
                                                  unsigned short* __restrict__ Hrelu) {
    int cg, rb;
    cell_decode(blockIdx.x, cg, rb);
    if (rb >= CELL_RB) return;
    __shared__ unsigned short lds[32 * 512];   // 32 KB
    const int lane = threadIdx.x & 63, wave = threadIdx.x >> 6;
    const int rl = lane & 15, kg = lane >> 4;
    const int col0 = cg * 16;
    for (int q = wave; q < 32; q += 4) {
        int s = q >> 2, kk = q & 3;
        const unsigned short* src = (s < 4 ? Wih + (size_t)s * 128 * KD
                                           : Whh + (size_t)(s - 4) * 128 * KD)
                                    + (size_t)(col0 + rl) * KD + kk * 32 + kg * 8;
        stage_frag(src, lds + q * 512);
    }
    __syncthreads();
    const int col = col0 + rl;
    const float b_i = bih[col] + bhh[col];
    const float b_f = bih[128 + col] + bhh[128 + col];
    const float b_g = bih[256 + col] + bhh[256 + col];
    const float b_o = bih[384 + col] + bhh[384 + col];
    int rt = rb * 4 + wave;
    if (rt >= RT_TILES) return;
    bf16x8 a1[4], a2[4];
    float cpre[4];
#pragma unroll
    for (int kk = 0; kk < 4; ++kk) {
        a1[kk] = ldfrag(Hh + ((size_t)rt * 16 + rl) * KD + kk * 32 + kg * 8);
        a2[kk] = ldfrag(Hx + ((size_t)rt * 16 + rl) * KD + kk * 32 + kg * 8);
    }
#pragma unroll
    for (int p = 0; p < 4; ++p)
        cpre[p] = Cx[(size_t)(rt * 16 + kg * 4 + p) * KD + col];
    while (rt < RT_TILES) {
        const int rtn = rt + CELL_STRIDE;
        bf16x8 n1[4], n2[4];
        float cnx[4];
        if (rtn < RT_TILES) {
#pragma unroll
            for (int kk = 0; kk < 4; ++kk) {
                n1[kk] = ldfrag(Hh + ((size_t)rtn * 16 + rl) * KD + kk * 32 + kg * 8);
                n2[kk] = ldfrag(Hx + ((size_t)rtn * 16 + rl) * KD + kk * 32 + kg * 8);
            }
#pragma unroll
            for (int p = 0; p < 4; ++p)
                cnx[p] = Cx[(size_t)(rtn * 16 + kg * 4 + p) * KD + col];
        }
        f32x4 gi = {0.f,0.f,0.f,0.f}, gf = gi, gg = gi, go = gi;
        f32x4 hi = gi, hf = gi, hg = gi, ho = gi;
#pragma unroll
        for (int kk = 0; kk < 4; ++kk) {
            gi = __builtin_amdgcn_mfma_f32_16x16x32_bf16(a1[kk], ldfrag(lds + (0*4+kk)*512 + lane*8), gi, 0, 0, 0);
            gf = __builtin_amdgcn_mfma_f32_16x16x32_bf16(a1[kk], ldfrag(lds + (1*4+kk)*512 + lane*8), gf, 0, 0, 0);
            gg = __builtin_amdgcn_mfma_f32_16x16x32_bf16(a1[kk], ldfrag(lds + (2*4+kk)*512 + lane*8), gg, 0, 0, 0);
            go = __builtin_amdgcn_mfma_f32_16x16x32_bf16(a1[kk], ldfrag(lds + (3*4+kk)*512 + lane*8), go, 0, 0, 0);
            hi = __builtin_amdgcn_mfma_f32_16x16x32_bf16(a2[kk], ldfrag(lds + (4*4+kk)*512 + lane*8), hi, 0, 0, 0);
            hf = __builtin_amdgcn_mfma_f32_16x16x32_bf16(a2[kk], ldfrag(lds + (5*4+kk)*512 + lane*8), hf, 0, 0, 0);
            hg = __builtin_amdgcn_mfma_f32_16x16x32_bf16(a2[kk], ldfrag(lds + (6*4+kk)*512 + lane*8), hg, 0, 0, 0);
            ho = __builtin_amdgcn_mfma_f32_16x16x32_bf16(a2[kk], ldfrag(lds + (7*4+kk)*512 + lane*8), ho, 0, 0, 0);
        }
#pragma unroll
        for (int p = 0; p < 4; ++p) {
            int row = rt * 16 + kg * 4 + p;
            size_t idx = (size_t)row * KD + col;
            float ig = fsig(gi[p] + hi[p] + b_i);
            float fg = fsig(gf[p] + hf[p] + b_f);
            float gv = ftanh(gg[p] + hg[p] + b_g);
            float og = fsig(go[p] + ho[p] + b_o);
            float c = fg * cpre[p] + ig * gv;
            float hn = og * ftanh(c);
            c_out[idx] = c;
            h_out[idx] = hn;
            Hrelu[idx] = f2bf(fmaxf(hn, 0.f));
        }
        rt = rtn;
#pragma unroll
        for (int kk = 0; kk < 4; ++kk) { a1[kk] = n1[kk]; a2[kk] = n2[kk]; }
#pragma unroll
        for (int p = 0; p < 4; ++p) cpre[p] = cnx[p];
    }
}

// ---------------------------------------------------------------------------
// head: out[N][64] = hrelu @ lin_wᵀ + lin_b; pipelined row-stride.
// ---------------------------------------------------------------------------
__global__ __launch_bounds__(256) void head_gemm(const unsigned short* __restrict__ Hr,
                                                 const unsigned short* __restrict__ LinW,
                                                 const float* __restrict__ lin_b,
                                                 float* __restrict__ Out) {
    __shared__ unsigned short wlds[16 * 512];
    const int lane = threadIdx.x & 63, wave = threadIdx.x >> 6;
    const int rl = lane & 15, kg = lane >> 4;
    for (int f = wave; f < 16; f += 4) {
        int jt = f >> 2, kk = f & 3;
        stage_frag(LinW + (size_t)(jt * 16 + rl) * KD + kk * 32 + kg * 8, wlds + f * 512);
    }
    __syncthreads();
    const int stride = gridDim.x << 2;
    int rt = blockIdx.x * 4 + wave;
    if (rt >= RT_TILES) return;
    bf16x8 a[4];
#pragma unroll
    for (int kk = 0; kk < 4; ++kk)
        a[kk] = ldfrag(Hr + ((size_t)rt * 16 + rl) * KD + kk * 32 + kg * 8);
    while (rt < RT_TILES) {
        const int rtn = rt + stride;
        bf16x8 an[4];
        if (rtn < RT_TILES) {
#pragma unroll
            for (int kk = 0; kk < 4; ++kk)
                an[kk] = ldfrag(Hr + ((size_t)rtn * 16 + rl) * KD + kk * 32 + kg * 8);
        }
#pragma unroll
        for (int jt = 0; jt < 4; ++jt) {
            f32x4 acc = {0.f, 0.f, 0.f, 0.f};
#pragma unroll
            for (int kk = 0; kk < 4; ++kk)
                acc = __builtin_amdgcn_mfma_f32_16x16x32_bf16(
                    a[kk], ldfrag(wlds + (jt * 4 + kk) * 512 + lane * 8), acc, 0, 0, 0);
            int col = jt * 16 + rl;
            float b = lin_b[col];
#pragma unroll
            for (int p = 0; p < 4; ++p)
                Out[(size_t)(rt * 16 + kg * 4 + p) * 64 + col] = acc[p] + b;
        }
        rt = rtn;
#pragma unroll
        for (int kk = 0; kk < 4; ++kk) a[kk] = an[kk];
    }
}

extern "C" void kernel_launch(void* const* d_in, const int* in_sizes, int n_in,
                              void* d_out, int out_size, void* d_ws, size_t ws_size,
                              hipStream_t stream) {
    const float* x        = (const float*)d_in[0];
    const int*   ei       = (const int*)d_in[1];
    const float* ew       = (const float*)d_in[2];
    const float* H        = (const float*)d_in[3];
    const float* C        = (const float*)d_in[4];
    const float* ggc_w    = (const float*)d_in[5];
    const float* gru_wih  = (const float*)d_in[6];
    const float* gru_whh  = (const float*)d_in[7];
    const float* gru_bih  = (const float*)d_in[8];
    const float* gru_bhh  = (const float*)d_in[9];
    const float* lstm_wih = (const float*)d_in[10];
    const float* lstm_whh = (const float*)d_in[11];
    const float* lstm_bih = (const float*)d_in[12];
    const float* lstm_bhh = (const float*)d_in[13];
    const float* lin_w    = (const float*)d_in[14];
    const float* lin_b    = (const float*)d_in[15];

    float* out_head = (float*)d_out;
    float* h_out = out_head + (size_t)N_NODES * 64;
    float* c_out = h_out + (size_t)N_NODES * KD;

    char* w = (char*)d_ws;
    unsigned short* hb    = (unsigned short*)w; w += (size_t)N_NODES * KD * 2;
    unsigned short* hb1   = (unsigned short*)w; w += (size_t)N_NODES * KD * 2;
    unsigned short* Hxb   = (unsigned short*)w; w += (size_t)N_NODES * KD * 2;
    unsigned short* mb    = (unsigned short*)w; w += (size_t)N_NODES * KD * 2;
    unsigned short* aggb  = (unsigned short*)w; w += (size_t)N_NODES * KD * 2;
    unsigned short* wgTb  = (unsigned short*)w; w += 2 * KD * KD * 2;
    unsigned short* wihb  = (unsigned short*)w; w += 384 * KD * 2;
    unsigned short* whhb  = (unsigned short*)w; w += 384 * KD * 2;
    unsigned short* lwihb = (unsigned short*)w; w += 512 * KD * 2;
    unsigned short* lwhhb = (unsigned short*)w; w += 512 * KD * 2;
    unsigned short* linwb = (unsigned short*)w; w += 64 * KD * 2;
    int*   rowptr = (int*)w; w += 50304 * 4;
    int*   cursor = (int*)w; w += 50304 * 4;
    int*   bsum   = (int*)w; w += 256 * 4;
    int*   sSrc   = (int*)w; w += (size_t)E_EDGES * 4;
    float* sW     = (float*)w; w += (size_t)E_EDGES * 4;

    dim3 blk(256);
    const int EB = (E_EDGES + 255) / 256;
    const int NF4 = N_NODES * KD / 4;
    const int CELL_BLOCKS = 1600;   // XCD-aware mapping (see cell_decode)

    cvt_xh<<<(2 * NF4 + 255) / 256, blk, 0, stream>>>(x, H, hb, Hxb, NF4);
    cvt_weights<<<(59392 + 255) / 256, blk, 0, stream>>>(
        gru_wih, gru_whh, lstm_wih, lstm_whh, lin_w,
        wihb, whhb, lwihb, lwhhb, linwb);
    transpose_wg_bf16<<<128, blk, 0, stream>>>(ggc_w, wgTb);

    hipMemsetAsync(cursor, 0, N_NODES * sizeof(int), stream);
    count_deg<<<EB, blk, 0, stream>>>(ei, cursor);
    scan_p1<<<NBLK_SCAN, blk, 0, stream>>>(cursor, rowptr, bsum);
    scan_p2<<<1, blk, 0, stream>>>(bsum, rowptr + N_NODES);
    scan_p3<<<NBLK_SCAN, blk, 0, stream>>>(bsum, rowptr, cursor);
    fill_csr<<<EB, blk, 0, stream>>>(ei, ew, cursor, sSrc, sW);

    mfma_gemm_m<<<391, blk, 0, stream>>>(hb, wgTb, mb);
    gather_agg_bf16<<<(N_NODES * 64 + 255) / 256, blk, 0, stream>>>(
        mb, rowptr, sSrc, sW, aggb);
    gru_fused<<<CELL_BLOCKS, blk, 0, stream>>>(aggb, hb, hb1, wihb, whhb, gru_bih, gru_bhh);

    mfma_gemm_m<<<391, blk, 0, stream>>>(hb1, wgTb + (size_t)KD * KD, mb);
    gather_agg_bf16<<<(N_NODES * 64 + 255) / 256, blk, 0, stream>>>(
        mb, rowptr, sSrc, sW, aggb);
    gru_fused<<<CELL_BLOCKS, blk, 0, stream>>>(aggb, hb1, hb, wihb, whhb, gru_bih, gru_bhh);

    lstm_fused<<<CELL_BLOCKS, blk, 0, stream>>>(hb, Hxb, C, lwihb, lwhhb,
                                                lstm_bih, lstm_bhh, h_out, c_out, mb);
    head_gemm<<<391, blk, 0, stream>>>(mb, linwb, lin_b, out_head);
}

// Round 11
// 339.680 us; speedup vs baseline: 1.1793x; 1.0363x over previous
//
#include <hip/hip_runtime.h>
#include <math.h>

#define N_NODES 50000
#define E_EDGES 800000
#define KD 128
#define NBLK_SCAN 196   // ceil(50000/256)
#define RT_TILES 3125   // N_NODES / 16 (exact)
#define CELL_RB 196     // rowblocks in cell kernels
#define CELL_STRIDE (CELL_RB * 4)

typedef __attribute__((ext_vector_type(8))) short bf16x8;
typedef __attribute__((ext_vector_type(4))) float f32x4;

__device__ __forceinline__ float fsig(float x) { return 1.f / (1.f + __expf(-x)); }
__device__ __forceinline__ float ftanh(float x) { return 1.f - 2.f / (1.f + __expf(2.f * x)); }

__device__ __forceinline__ unsigned short f2bf(float f) {
    unsigned u = __float_as_uint(f);
    return (unsigned short)((u + 0x7FFFu + ((u >> 16) & 1u)) >> 16);
}
__device__ __forceinline__ float bf2f(unsigned short b) {
    return __uint_as_float(((unsigned)b) << 16);
}
__device__ __forceinline__ bf16x8 ldfrag(const unsigned short* p) {
    return *(const bf16x8*)(const void*)p;
}
__device__ __forceinline__ void stage_frag(const unsigned short* g, unsigned short* l) {
    __builtin_amdgcn_global_load_lds(
        (const __attribute__((address_space(1))) unsigned int*)g,
        (__attribute__((address_space(3))) unsigned int*)l, 16, 0, 0);
}
// XCD-aware decode: 8 colgroup-sharers of a rowblock get ids spaced 8 apart
// (same id%8 -> same XCD, co-resident); consecutive rowblocks rotate XCDs.
// [R9 measured: lstm FETCH 125 MB -> 26.8 MB]
__device__ __forceinline__ void cell_decode(int id, int& x, int& y) {
    y = ((id >> 6) << 3) + (id & 7);   // rowblock 0..199 (>=196 invalid)
    x = (id >> 3) & 7;                 // colgroup 0..7
}

// ---------------------------------------------------------------------------
// fp32 -> bf16 converts
// ---------------------------------------------------------------------------
__global__ __launch_bounds__(256) void cvt_xh(const float* __restrict__ x,
                                              const float* __restrict__ H,
                                              unsigned short* __restrict__ hb,
                                              unsigned short* __restrict__ Hxb, int n4) {
    int t = blockIdx.x * 256 + threadIdx.x;
    const float* in; unsigned short* out; int idx;
    if (t < n4) { in = x; out = hb; idx = t; }
    else if (t < 2 * n4) { in = H; out = Hxb; idx = t - n4; }
    else return;
    float4 v = ((const float4*)in)[idx];
    ushort4 o;
    o.x = f2bf(v.x); o.y = f2bf(v.y); o.z = f2bf(v.z); o.w = f2bf(v.w);
    ((ushort4*)out)[idx] = o;
}

__global__ __launch_bounds__(256) void cvt_weights(
        const float* __restrict__ b,
        const float* __restrict__ c, const float* __restrict__ d,
        const float* __restrict__ e,
        unsigned short* __restrict__ ob,
        unsigned short* __restrict__ oc, unsigned short* __restrict__ od,
        unsigned short* __restrict__ oe) {
    int t = blockIdx.x * 256 + threadIdx.x;
    const float* in; unsigned short* out; int idx;
    if      (t < 12288)  { in = b; out = ob; idx = t; }            // gru_whh
    else if (t < 28672)  { in = c; out = oc; idx = t - 12288; }    // lstm_wih
    else if (t < 45056)  { in = d; out = od; idx = t - 28672; }    // lstm_whh
    else if (t < 47104)  { in = e; out = oe; idx = t - 45056; }    // lin_w
    else return;
    float4 v = ((const float4*)in)[idx];
    ushort4 o;
    o.x = f2bf(v.x); o.y = f2bf(v.y); o.z = f2bf(v.z); o.w = f2bf(v.w);
    ((ushort4*)out)[idx] = o;
}

// ---------------------------------------------------------------------------
// Fused GGC+GRU-input weight: WfT[l][j][k] = sum_c Wg[l][k][c] * Wih[j][c]
// (linearity: agg@Wih^T = (A_w h)@Wg@Wih^T). fp32 accum -> bf16.
// ---------------------------------------------------------------------------
__global__ __launch_bounds__(128) void fuse_wg_wih(const float* __restrict__ Wg,
                                                   const float* __restrict__ Wih,
                                                   unsigned short* __restrict__ WfT) {
    __shared__ float wi[128];
    const int j = blockIdx.x;        // 0..383
    const int l = blockIdx.y;        // 0..1
    const int k = threadIdx.x;       // 0..127
    wi[k] = Wih[j * 128 + k];
    __syncthreads();
    const float* wg = Wg + l * 16384 + k * 128;
    float s = 0.f;
#pragma unroll 8
    for (int c = 0; c < 128; c += 4) {
        float4 a = *(const float4*)(wg + c);
        s += a.x * wi[c] + a.y * wi[c + 1] + a.z * wi[c + 2] + a.w * wi[c + 3];
    }
    WfT[((size_t)l * 384 + j) * 128 + k] = f2bf(s);
}

// ---------------------------------------------------------------------------
// CSR build
// ---------------------------------------------------------------------------
__global__ __launch_bounds__(256) void count_deg(const int* __restrict__ ei,
                                                 int* __restrict__ deg) {
    int e = blockIdx.x * 256 + threadIdx.x;
    if (e >= E_EDGES) return;
    atomicAdd(&deg[ei[E_EDGES + e]], 1);
}

__global__ __launch_bounds__(256) void scan_p1(const int* __restrict__ deg,
                                               int* __restrict__ excl,
                                               int* __restrict__ bsum) {
    __shared__ int part[256];
    const int t = threadIdx.x;
    const int i = blockIdx.x * 256 + t;
    int v = (i < N_NODES) ? deg[i] : 0;
    part[t] = v;
    __syncthreads();
#pragma unroll
    for (int off = 1; off < 256; off <<= 1) {
        int u = (t >= off) ? part[t - off] : 0;
        __syncthreads();
        part[t] += u;
        __syncthreads();
    }
    if (i < N_NODES) excl[i] = part[t] - v;
    if (t == 255) bsum[blockIdx.x] = part[255];
}

__global__ __launch_bounds__(256) void scan_p2(int* __restrict__ bsum,
                                               int* __restrict__ rowptrN) {
    __shared__ int part[256];
    const int t = threadIdx.x;
    int v = (t < NBLK_SCAN) ? bsum[t] : 0;
    part[t] = v;
    __syncthreads();
#pragma unroll
    for (int off = 1; off < 256; off <<= 1) {
        int u = (t >= off) ? part[t - off] : 0;
        __syncthreads();
        part[t] += u;
        __syncthreads();
    }
    if (t < NBLK_SCAN) bsum[t] = part[t] - v;
    if (t == 255) *rowptrN = part[255];
}

__global__ __launch_bounds__(256) void scan_p3(const int* __restrict__ bsum,
                                               int* __restrict__ rowptr,
                                               int* __restrict__ cursor) {
    int i = blockIdx.x * 256 + threadIdx.x;
    if (i >= N_NODES) return;
    int r = rowptr[i] + bsum[blockIdx.x];
    rowptr[i] = r;
    cursor[i] = r;
}

__global__ __launch_bounds__(256) void fill_csr(const int* __restrict__ ei,
                                                const float* __restrict__ ew,
                                                int* __restrict__ cursor,
                                                int* __restrict__ sSrc,
                                                float* __restrict__ sW) {
    int e = blockIdx.x * 256 + threadIdx.x;
    if (e >= E_EDGES) return;
    int dst = ei[E_EDGES + e];
    int pos = atomicAdd(&cursor[dst], 1);
    sSrc[pos] = ei[e];
    sW[pos] = ew[e];
}

// ---------------------------------------------------------------------------
// gh[n,:] = sum_e w[e]*h[src[e],:]; one node/wave, index prefetch
// ---------------------------------------------------------------------------
__global__ __launch_bounds__(256) void gather_agg_bf16(const unsigned short* __restrict__ m,
                                                       const int* __restrict__ rowptr,
                                                       const int* __restrict__ sSrc,
                                                       const float* __restrict__ sW,
                                                       unsigned short* __restrict__ agg) {
    int wid = (blockIdx.x * 256 + threadIdx.x) >> 6;
    if (wid >= N_NODES) return;
    int lane = threadIdx.x & 63;
    int half = lane >> 5, li = lane & 31;
    int f0 = li << 2;
    int e0 = rowptr[wid], e1 = rowptr[wid + 1];
    float ax = 0.f, ay = 0.f, az = 0.f, aw = 0.f;
    int e = e0 + half;
    int s_nx = 0; float w_nx = 0.f;
    if (e < e1) { s_nx = sSrc[e]; w_nx = sW[e]; }
    for (; e < e1; e += 2) {
        int s = s_nx; float ww = w_nx;
        int en = e + 2;
        if (en < e1) { s_nx = sSrc[en]; w_nx = sW[en]; }
        ushort4 v = *(const ushort4*)(m + (size_t)s * KD + f0);
        ax += ww * bf2f(v.x); ay += ww * bf2f(v.y);
        az += ww * bf2f(v.z); aw += ww * bf2f(v.w);
    }
    ax += __shfl_xor(ax, 32, 64);
    ay += __shfl_xor(ay, 32, 64);
    az += __shfl_xor(az, 32, 64);
    aw += __shfl_xor(aw, 32, 64);
    if (half == 0) {
        ushort4 o;
        o.x = f2bf(ax); o.y = f2bf(ay); o.z = f2bf(az); o.w = f2bf(aw);
        *(ushort4*)(agg + (size_t)wid * KD + f0) = o;
    }
}

// ---------------------------------------------------------------------------
// Fused GRU, col-split 8, XCD-aware mapping. Wih here is the FUSED weight
// (Wg·gru_wih^T), so input gates = gathered_h @ WfT. Pipelined A-loads.
// ---------------------------------------------------------------------------
__global__ __launch_bounds__(256) void gru_fused(const unsigned short* __restrict__ Agg,
                                                 const unsigned short* __restrict__ Hin,
                                                 unsigned short* __restrict__ Hout,
                                                 const unsigned short* __restrict__ Wih,
                                                 const unsigned short* __restrict__ Whh,
                                                 const float* __restrict__ bih,
                                                 const float* __restrict__ bhh) {
    int cg, rb;
    cell_decode(blockIdx.x, cg, rb);
    if (rb >= CELL_RB) return;
    __shared__ unsigned short lds[24 * 512];   // 24 KB
    const int lane = threadIdx.x & 63, wave = threadIdx.x >> 6;
    const int rl = lane & 15, kg = lane >> 4;
    const int col0 = cg * 16;
    for (int q = wave; q < 24; q += 4) {
        int s = q >> 2, kk = q & 3;
        const unsigned short* src = (s < 3 ? Wih + (size_t)s * 128 * KD
                                           : Whh + (size_t)(s - 3) * 128 * KD)
                                    + (size_t)(col0 + rl) * KD + kk * 32 + kg * 8;
        stage_frag(src, lds + q * 512);
    }
    __syncthreads();
    const int col = col0 + rl;
    const float b_ir = bih[col], b_iz = bih[128 + col], b_in = bih[256 + col];
    const float b_hr = bhh[col], b_hz = bhh[128 + col], b_hn = bhh[256 + col];
    int rt = rb * 4 + wave;
    if (rt >= RT_TILES) return;
    bf16x8 a1[4], a2[4];
#pragma unroll
    for (int kk = 0; kk < 4; ++kk) {
        a1[kk] = ldfrag(Agg + ((size_t)rt * 16 + rl) * KD + kk * 32 + kg * 8);
        a2[kk] = ldfrag(Hin + ((size_t)rt * 16 + rl) * KD + kk * 32 + kg * 8);
    }
    while (rt < RT_TILES) {
        const int rtn = rt + CELL_STRIDE;
        bf16x8 n1[4], n2[4];
        if (rtn < RT_TILES) {
#pragma unroll
            for (int kk = 0; kk < 4; ++kk) {
                n1[kk] = ldfrag(Agg + ((size_t)rtn * 16 + rl) * KD + kk * 32 + kg * 8);
                n2[kk] = ldfrag(Hin + ((size_t)rtn * 16 + rl) * KD + kk * 32 + kg * 8);
            }
        }
        f32x4 ir = {0.f,0.f,0.f,0.f}, iz = ir, in_ = ir, hr = ir, hz = ir, hn = ir;
#pragma unroll
        for (int kk = 0; kk < 4; ++kk) {
            ir  = __builtin_amdgcn_mfma_f32_16x16x32_bf16(a1[kk], ldfrag(lds + (0*4+kk)*512 + lane*8), ir,  0, 0, 0);
            iz  = __builtin_amdgcn_mfma_f32_16x16x32_bf16(a1[kk], ldfrag(lds + (1*4+kk)*512 + lane*8), iz,  0, 0, 0);
            in_ = __builtin_amdgcn_mfma_f32_16x16x32_bf16(a1[kk], ldfrag(lds + (2*4+kk)*512 + lane*8), in_, 0, 0, 0);
            hr  = __builtin_amdgcn_mfma_f32_16x16x32_bf16(a2[kk], ldfrag(lds + (3*4+kk)*512 + lane*8), hr,  0, 0, 0);
            hz  = __builtin_amdgcn_mfma_f32_16x16x32_bf16(a2[kk], ldfrag(lds + (4*4+kk)*512 + lane*8), hz,  0, 0, 0);
            hn  = __builtin_amdgcn_mfma_f32_16x16x32_bf16(a2[kk], ldfrag(lds + (5*4+kk)*512 + lane*8), hn,  0, 0, 0);
        }
#pragma unroll
        for (int p = 0; p < 4; ++p) {
            int row = rt * 16 + kg * 4 + p;
            float r = fsig(ir[p] + b_ir + hr[p] + b_hr);
            float z = fsig(iz[p] + b_iz + hz[p] + b_hz);
            float nc = ftanh(in_[p] + b_in + r * (hn[p] + b_hn));
            float hv = bf2f(Hin[(size_t)row * KD + col]);
            Hout[(size_t)row * KD + col] = f2bf((1.f - z) * nc + z * hv);
        }
        rt = rtn;
#pragma unroll
        for (int kk = 0; kk < 4; ++kk) { a1[kk] = n1[kk]; a2[kk] = n2[kk]; }
    }
}

// ---------------------------------------------------------------------------
// Fused LSTM, col-split 8, XCD-aware mapping; pipelined A/Cx loads.
// ---------------------------------------------------------------------------
__global__ __launch_bounds__(256) void lstm_fused(const unsigned short* __restrict__ Hh,
                                                  const unsigned short* __restrict__ Hx,
                                                  const float* __restrict__ Cx,
                                                  const unsigned short* __restrict__ Wih,
                                                  const unsigned short* __restrict__ Whh,
                                                  const float* __restrict__ bih,
                                                  const float* __restrict__ bhh,
                                                  float* __restrict__ h_out,
                                                  float* __restrict__ c_out,
                                                  unsigned short* __restrict__ Hrelu) {
    int cg, rb;
    cell_decode(blockIdx.x, cg, rb);
    if (rb >= CELL_RB) return;
    __shared__ unsigned short lds[32 * 512];   // 32 KB
    const int lane = threadIdx.x & 63, wave = threadIdx.x >> 6;
    const int rl = lane & 15, kg = lane >> 4;
    const int col0 = cg * 16;
    for (int q = wave; q < 32; q += 4) {
        int s = q >> 2, kk = q & 3;
        const unsigned short* src = (s < 4 ? Wih + (size_t)s * 128 * KD
                                           : Whh + (size_t)(s - 4) * 128 * KD)
                                    + (size_t)(col0 + rl) * KD + kk * 32 + kg * 8;
        stage_frag(src, lds + q * 512);
    }
    __syncthreads();
    const int col = col0 + rl;
    const float b_i = bih[col] + bhh[col];
    const float b_f = bih[128 + col] + bhh[128 + col];
    const float b_g = bih[256 + col] + bhh[256 + col];
    const float b_o = bih[384 + col] + bhh[384 + col];
    int rt = rb * 4 + wave;
    if (rt >= RT_TILES) return;
    bf16x8 a1[4], a2[4];
    float cpre[4];
#pragma unroll
    for (int kk = 0; kk < 4; ++kk) {
        a1[kk] = ldfrag(Hh + ((size_t)rt * 16 + rl) * KD + kk * 32 + kg * 8);
        a2[kk] = ldfrag(Hx + ((size_t)rt * 16 + rl) * KD + kk * 32 + kg * 8);
    }
#pragma unroll
    for (int p = 0; p < 4; ++p)
        cpre[p] = Cx[(size_t)(rt * 16 + kg * 4 + p) * KD + col];
    while (rt < RT_TILES) {
        const int rtn = rt + CELL_STRIDE;
        bf16x8 n1[4], n2[4];
        float cnx[4];
        if (rtn < RT_TILES) {
#pragma unroll
            for (int kk = 0; kk < 4; ++kk) {
                n1[kk] = ldfrag(Hh + ((size_t)rtn * 16 + rl) * KD + kk * 32 + kg * 8);
                n2[kk] = ldfrag(Hx + ((size_t)rtn * 16 + rl) * KD + kk * 32 + kg * 8);
            }
#pragma unroll
            for (int p = 0; p < 4; ++p)
                cnx[p] = Cx[(size_t)(rtn * 16 + kg * 4 + p) * KD + col];
        }
        f32x4 gi = {0.f,0.f,0.f,0.f}, gf = gi, gg = gi, go = gi;
        f32x4 hi = gi, hf = gi, hg = gi, ho = gi;
#pragma unroll
        for (int kk = 0; kk < 4; ++kk) {
            gi = __builtin_amdgcn_mfma_f32_16x16x32_bf16(a1[kk], ldfrag(lds + (0*4+kk)*512 + lane*8), gi, 0, 0, 0);
            gf = __builtin_amdgcn_mfma_f32_16x16x32_bf16(a1[kk], ldfrag(lds + (1*4+kk)*512 + lane*8), gf, 0, 0, 0);
            gg = __builtin_amdgcn_mfma_f32_16x16x32_bf16(a1[kk], ldfrag(lds + (2*4+kk)*512 + lane*8), gg, 0, 0, 0);
            go = __builtin_amdgcn_mfma_f32_16x16x32_bf16(a1[kk], ldfrag(lds + (3*4+kk)*512 + lane*8), go, 0, 0, 0);
            hi = __builtin_amdgcn_mfma_f32_16x16x32_bf16(a2[kk], ldfrag(lds + (4*4+kk)*512 + lane*8), hi, 0, 0, 0);
            hf = __builtin_amdgcn_mfma_f32_16x16x32_bf16(a2[kk], ldfrag(lds + (5*4+kk)*512 + lane*8), hf, 0, 0, 0);
            hg = __builtin_amdgcn_mfma_f32_16x16x32_bf16(a2[kk], ldfrag(lds + (6*4+kk)*512 + lane*8), hg, 0, 0, 0);
            ho = __builtin_amdgcn_mfma_f32_16x16x32_bf16(a2[kk], ldfrag(lds + (7*4+kk)*512 + lane*8), ho, 0, 0, 0);
        }
#pragma unroll
        for (int p = 0; p < 4; ++p) {
            int row = rt * 16 + kg * 4 + p;
            size_t idx = (size_t)row * KD + col;
            float ig = fsig(gi[p] + hi[p] + b_i);
            float fg = fsig(gf[p] + hf[p] + b_f);
            float gv = ftanh(gg[p] + hg[p] + b_g);
            float og = fsig(go[p] + ho[p] + b_o);
            float c = fg * cpre[p] + ig * gv;
            float hn = og * ftanh(c);
            c_out[idx] = c;
            h_out[idx] = hn;
            Hrelu[idx] = f2bf(fmaxf(hn, 0.f));
        }
        rt = rtn;
#pragma unroll
        for (int kk = 0; kk < 4; ++kk) { a1[kk] = n1[kk]; a2[kk] = n2[kk]; }
#pragma unroll
        for (int p = 0; p < 4; ++p) cpre[p] = cnx[p];
    }
}

// ---------------------------------------------------------------------------
// head: out[N][64] = hrelu @ lin_wᵀ + lin_b; pipelined row-stride.
// ---------------------------------------------------------------------------
__global__ __launch_bounds__(256) void head_gemm(const unsigned short* __restrict__ Hr,
                                                 const unsigned short* __restrict__ LinW,
                                                 const float* __restrict__ lin_b,
                                                 float* __restrict__ Out) {
    __shared__ unsigned short wlds[16 * 512];
    const int lane = threadIdx.x & 63, wave = threadIdx.x >> 6;
    const int rl = lane & 15, kg = lane >> 4;
    for (int f = wave; f < 16; f += 4) {
        int jt = f >> 2, kk = f & 3;
        stage_frag(LinW + (size_t)(jt * 16 + rl) * KD + kk * 32 + kg * 8, wlds + f * 512);
    }
    __syncthreads();
    const int stride = gridDim.x << 2;
    int rt = blockIdx.x * 4 + wave;
    if (rt >= RT_TILES) return;
    bf16x8 a[4];
#pragma unroll
    for (int kk = 0; kk < 4; ++kk)
        a[kk] = ldfrag(Hr + ((size_t)rt * 16 + rl) * KD + kk * 32 + kg * 8);
    while (rt < RT_TILES) {
        const int rtn = rt + stride;
        bf16x8 an[4];
        if (rtn < RT_TILES) {
#pragma unroll
            for (int kk = 0; kk < 4; ++kk)
                an[kk] = ldfrag(Hr + ((size_t)rtn * 16 + rl) * KD + kk * 32 + kg * 8);
        }
#pragma unroll
        for (int jt = 0; jt < 4; ++jt) {
            f32x4 acc = {0.f, 0.f, 0.f, 0.f};
#pragma unroll
            for (int kk = 0; kk < 4; ++kk)
                acc = __builtin_amdgcn_mfma_f32_16x16x32_bf16(
                    a[kk], ldfrag(wlds + (jt * 4 + kk) * 512 + lane * 8), acc, 0, 0, 0);
            int col = jt * 16 + rl;
            float b = lin_b[col];
#pragma unroll
            for (int p = 0; p < 4; ++p)
                Out[(size_t)(rt * 16 + kg * 4 + p) * 64 + col] = acc[p] + b;
        }
        rt = rtn;
#pragma unroll
        for (int kk = 0; kk < 4; ++kk) a[kk] = an[kk];
    }
}

extern "C" void kernel_launch(void* const* d_in, const int* in_sizes, int n_in,
                              void* d_out, int out_size, void* d_ws, size_t ws_size,
                              hipStream_t stream) {
    const float* x        = (const float*)d_in[0];
    const int*   ei       = (const int*)d_in[1];
    const float* ew       = (const float*)d_in[2];
    const float* H        = (const float*)d_in[3];
    const float* C        = (const float*)d_in[4];
    const float* ggc_w    = (const float*)d_in[5];
    const float* gru_wih  = (const float*)d_in[6];
    const float* gru_whh  = (const float*)d_in[7];
    const float* gru_bih  = (const float*)d_in[8];
    const float* gru_bhh  = (const float*)d_in[9];
    const float* lstm_wih = (const float*)d_in[10];
    const float* lstm_whh = (const float*)d_in[11];
    const float* lstm_bih = (const float*)d_in[12];
    const float* lstm_bhh = (const float*)d_in[13];
    const float* lin_w    = (const float*)d_in[14];
    const float* lin_b    = (const float*)d_in[15];

    float* out_head = (float*)d_out;
    float* h_out = out_head + (size_t)N_NODES * 64;
    float* c_out = h_out + (size_t)N_NODES * KD;

    char* w = (char*)d_ws;
    unsigned short* hb    = (unsigned short*)w; w += (size_t)N_NODES * KD * 2;
    unsigned short* hb1   = (unsigned short*)w; w += (size_t)N_NODES * KD * 2;
    unsigned short* Hxb   = (unsigned short*)w; w += (size_t)N_NODES * KD * 2;
    unsigned short* mb    = (unsigned short*)w; w += (size_t)N_NODES * KD * 2;  // Hrelu
    unsigned short* aggb  = (unsigned short*)w; w += (size_t)N_NODES * KD * 2;  // gathered h
    unsigned short* WfT   = (unsigned short*)w; w += 2 * 384 * KD * 2;          // fused Wg·Wih^T
    unsigned short* whhb  = (unsigned short*)w; w += 384 * KD * 2;
    unsigned short* lwihb = (unsigned short*)w; w += 512 * KD * 2;
    unsigned short* lwhhb = (unsigned short*)w; w += 512 * KD * 2;
    unsigned short* linwb = (unsigned short*)w; w += 64 * KD * 2;
    int*   rowptr = (int*)w; w += 50304 * 4;
    int*   cursor = (int*)w; w += 50304 * 4;
    int*   bsum   = (int*)w; w += 256 * 4;
    int*   sSrc   = (int*)w; w += (size_t)E_EDGES * 4;
    float* sW     = (float*)w; w += (size_t)E_EDGES * 4;

    dim3 blk(256);
    const int EB = (E_EDGES + 255) / 256;
    const int NF4 = N_NODES * KD / 4;
    const int CELL_BLOCKS = 1600;   // XCD-aware mapping (cell_decode)

    cvt_xh<<<(2 * NF4 + 255) / 256, blk, 0, stream>>>(x, H, hb, Hxb, NF4);
    cvt_weights<<<(47104 + 255) / 256, blk, 0, stream>>>(
        gru_whh, lstm_wih, lstm_whh, lin_w,
        whhb, lwihb, lwhhb, linwb);
    fuse_wg_wih<<<dim3(384, 2), 128, 0, stream>>>(ggc_w, gru_wih, WfT);

    hipMemsetAsync(cursor, 0, N_NODES * sizeof(int), stream);
    count_deg<<<EB, blk, 0, stream>>>(ei, cursor);
    scan_p1<<<NBLK_SCAN, blk, 0, stream>>>(cursor, rowptr, bsum);
    scan_p2<<<1, blk, 0, stream>>>(bsum, rowptr + N_NODES);
    scan_p3<<<NBLK_SCAN, blk, 0, stream>>>(bsum, rowptr, cursor);
    fill_csr<<<EB, blk, 0, stream>>>(ei, ew, cursor, sSrc, sW);

    // layer 0: gh = A_w·h ; h' = GRU(gh@Wf0, h)
    gather_agg_bf16<<<(N_NODES * 64 + 255) / 256, blk, 0, stream>>>(
        hb, rowptr, sSrc, sW, aggb);
    gru_fused<<<CELL_BLOCKS, blk, 0, stream>>>(aggb, hb, hb1,
                                               WfT, whhb, gru_bih, gru_bhh);
    // layer 1
    gather_agg_bf16<<<(N_NODES * 64 + 255) / 256, blk, 0, stream>>>(
        hb1, rowptr, sSrc, sW, aggb);
    gru_fused<<<CELL_BLOCKS, blk, 0, stream>>>(aggb, hb1, hb,
                                               WfT + (size_t)384 * KD, whhb, gru_bih, gru_bhh);

    lstm_fused<<<CELL_BLOCKS, blk, 0, stream>>>(hb, Hxb, C, lwihb, lwhhb,
                                                lstm_bih, lstm_bhh, h_out, c_out, mb);
    head_gemm<<<391, blk, 0, stream>>>(mb, linwb, lin_b, out_head);
}

// Round 12
// 312.256 us; speedup vs baseline: 1.2828x; 1.0878x over previous
//
#include <hip/hip_runtime.h>
#include <math.h>

#define N_NODES 50000
#define E_EDGES 800000
#define KD 128
#define NBLK_SCAN 196   // ceil(50000/256)
#define RT_TILES 3125   // N_NODES / 16 (exact)
#define CELL_RB 128     // rowblocks in cell kernels (persistent: 4 blocks/CU)
#define CELL_STRIDE (CELL_RB * 4)
#define CELL_BLOCKS 1024

typedef __attribute__((ext_vector_type(8))) short bf16x8;
typedef __attribute__((ext_vector_type(4))) float f32x4;

__device__ __forceinline__ float fsig(float x) { return 1.f / (1.f + __expf(-x)); }
__device__ __forceinline__ float ftanh(float x) { return 1.f - 2.f / (1.f + __expf(2.f * x)); }

__device__ __forceinline__ unsigned short f2bf(float f) {
    unsigned u = __float_as_uint(f);
    return (unsigned short)((u + 0x7FFFu + ((u >> 16) & 1u)) >> 16);
}
__device__ __forceinline__ float bf2f(unsigned short b) {
    return __uint_as_float(((unsigned)b) << 16);
}
__device__ __forceinline__ bf16x8 ldfrag(const unsigned short* p) {
    return *(const bf16x8*)(const void*)p;
}
__device__ __forceinline__ void stage_frag(const unsigned short* g, unsigned short* l) {
    __builtin_amdgcn_global_load_lds(
        (const __attribute__((address_space(1))) unsigned int*)g,
        (__attribute__((address_space(3))) unsigned int*)l, 16, 0, 0);
}
// XCD-aware decode: 8 colgroup-sharers of a rowblock get ids spaced 8 apart
// (same id%8 -> same XCD, co-resident). [R9 measured: FETCH 125 -> 26.8 MB]
// 1024 blocks = 128 rowblocks x 8 colgroups, exactly 4 blocks/CU resident.
__device__ __forceinline__ void cell_decode(int id, int& x, int& y) {
    y = ((id >> 6) << 3) + (id & 7);   // rowblock 0..127
    x = (id >> 3) & 7;                 // colgroup 0..7
}

// ---------------------------------------------------------------------------
// fp32 -> bf16 converts
// ---------------------------------------------------------------------------
__global__ __launch_bounds__(256) void cvt_xh(const float* __restrict__ x,
                                              const float* __restrict__ H,
                                              unsigned short* __restrict__ hb,
                                              unsigned short* __restrict__ Hxb, int n4) {
    int t = blockIdx.x * 256 + threadIdx.x;
    const float* in; unsigned short* out; int idx;
    if (t < n4) { in = x; out = hb; idx = t; }
    else if (t < 2 * n4) { in = H; out = Hxb; idx = t - n4; }
    else return;
    float4 v = ((const float4*)in)[idx];
    ushort4 o;
    o.x = f2bf(v.x); o.y = f2bf(v.y); o.z = f2bf(v.z); o.w = f2bf(v.w);
    ((ushort4*)out)[idx] = o;
}

__global__ __launch_bounds__(256) void cvt_weights(
        const float* __restrict__ b,
        const float* __restrict__ c, const float* __restrict__ d,
        const float* __restrict__ e,
        unsigned short* __restrict__ ob,
        unsigned short* __restrict__ oc, unsigned short* __restrict__ od,
        unsigned short* __restrict__ oe) {
    int t = blockIdx.x * 256 + threadIdx.x;
    const float* in; unsigned short* out; int idx;
    if      (t < 12288)  { in = b; out = ob; idx = t; }            // gru_whh
    else if (t < 28672)  { in = c; out = oc; idx = t - 12288; }    // lstm_wih
    else if (t < 45056)  { in = d; out = od; idx = t - 28672; }    // lstm_whh
    else if (t < 47104)  { in = e; out = oe; idx = t - 45056; }    // lin_w
    else return;
    float4 v = ((const float4*)in)[idx];
    ushort4 o;
    o.x = f2bf(v.x); o.y = f2bf(v.y); o.z = f2bf(v.z); o.w = f2bf(v.w);
    ((ushort4*)out)[idx] = o;
}

// ---------------------------------------------------------------------------
// Fused GGC+GRU-input weight: WfT[l][j][k] = sum_c Wg[l][k][c] * Wih[j][c]
// ---------------------------------------------------------------------------
__global__ __launch_bounds__(128) void fuse_wg_wih(const float* __restrict__ Wg,
                                                   const float* __restrict__ Wih,
                                                   unsigned short* __restrict__ WfT) {
    __shared__ float wi[128];
    const int j = blockIdx.x;
    const int l = blockIdx.y;
    const int k = threadIdx.x;
    wi[k] = Wih[j * 128 + k];
    __syncthreads();
    const float* wg = Wg + l * 16384 + k * 128;
    float s = 0.f;
#pragma unroll 8
    for (int c = 0; c < 128; c += 4) {
        float4 a = *(const float4*)(wg + c);
        s += a.x * wi[c] + a.y * wi[c + 1] + a.z * wi[c + 2] + a.w * wi[c + 3];
    }
    WfT[((size_t)l * 384 + j) * 128 + k] = f2bf(s);
}

// ---------------------------------------------------------------------------
// CSR build
// ---------------------------------------------------------------------------
__global__ __launch_bounds__(256) void count_deg(const int* __restrict__ ei,
                                                 int* __restrict__ deg) {
    int e = blockIdx.x * 256 + threadIdx.x;
    if (e >= E_EDGES) return;
    atomicAdd(&deg[ei[E_EDGES + e]], 1);
}

__global__ __launch_bounds__(256) void scan_p1(const int* __restrict__ deg,
                                               int* __restrict__ excl,
                                               int* __restrict__ bsum) {
    __shared__ int part[256];
    const int t = threadIdx.x;
    const int i = blockIdx.x * 256 + t;
    int v = (i < N_NODES) ? deg[i] : 0;
    part[t] = v;
    __syncthreads();
#pragma unroll
    for (int off = 1; off < 256; off <<= 1) {
        int u = (t >= off) ? part[t - off] : 0;
        __syncthreads();
        part[t] += u;
        __syncthreads();
    }
    if (i < N_NODES) excl[i] = part[t] - v;
    if (t == 255) bsum[blockIdx.x] = part[255];
}

__global__ __launch_bounds__(256) void scan_p2(int* __restrict__ bsum,
                                               int* __restrict__ rowptrN) {
    __shared__ int part[256];
    const int t = threadIdx.x;
    int v = (t < NBLK_SCAN) ? bsum[t] : 0;
    part[t] = v;
    __syncthreads();
#pragma unroll
    for (int off = 1; off < 256; off <<= 1) {
        int u = (t >= off) ? part[t - off] : 0;
        __syncthreads();
        part[t] += u;
        __syncthreads();
    }
    if (t < NBLK_SCAN) bsum[t] = part[t] - v;
    if (t == 255) *rowptrN = part[255];
}

__global__ __launch_bounds__(256) void scan_p3(const int* __restrict__ bsum,
                                               int* __restrict__ rowptr,
                                               int* __restrict__ cursor) {
    int i = blockIdx.x * 256 + threadIdx.x;
    if (i >= N_NODES) return;
    int r = rowptr[i] + bsum[blockIdx.x];
    rowptr[i] = r;
    cursor[i] = r;
}

__global__ __launch_bounds__(256) void fill_csr(const int* __restrict__ ei,
                                                const float* __restrict__ ew,
                                                int* __restrict__ cursor,
                                                int* __restrict__ sSrc,
                                                float* __restrict__ sW) {
    int e = blockIdx.x * 256 + threadIdx.x;
    if (e >= E_EDGES) return;
    int dst = ei[E_EDGES + e];
    int pos = atomicAdd(&cursor[dst], 1);
    sSrc[pos] = ei[e];
    sW[pos] = ew[e];
}

// ---------------------------------------------------------------------------
// gh[n,:] = sum_e w[e]*h[src[e],:]; one node/wave, index prefetch
// ---------------------------------------------------------------------------
__global__ __launch_bounds__(256) void gather_agg_bf16(const unsigned short* __restrict__ m,
                                                       const int* __restrict__ rowptr,
                                                       const int* __restrict__ sSrc,
                                                       const float* __restrict__ sW,
                                                       unsigned short* __restrict__ agg) {
    int wid = (blockIdx.x * 256 + threadIdx.x) >> 6;
    if (wid >= N_NODES) return;
    int lane = threadIdx.x & 63;
    int half = lane >> 5, li = lane & 31;
    int f0 = li << 2;
    int e0 = rowptr[wid], e1 = rowptr[wid + 1];
    float ax = 0.f, ay = 0.f, az = 0.f, aw = 0.f;
    int e = e0 + half;
    int s_nx = 0; float w_nx = 0.f;
    if (e < e1) { s_nx = sSrc[e]; w_nx = sW[e]; }
    for (; e < e1; e += 2) {
        int s = s_nx; float ww = w_nx;
        int en = e + 2;
        if (en < e1) { s_nx = sSrc[en]; w_nx = sW[en]; }
        ushort4 v = *(const ushort4*)(m + (size_t)s * KD + f0);
        ax += ww * bf2f(v.x); ay += ww * bf2f(v.y);
        az += ww * bf2f(v.z); aw += ww * bf2f(v.w);
    }
    ax += __shfl_xor(ax, 32, 64);
    ay += __shfl_xor(ay, 32, 64);
    az += __shfl_xor(az, 32, 64);
    aw += __shfl_xor(aw, 32, 64);
    if (half == 0) {
        ushort4 o;
        o.x = f2bf(ax); o.y = f2bf(ay); o.z = f2bf(az); o.w = f2bf(aw);
        *(ushort4*)(agg + (size_t)wid * KD + f0) = o;
    }
}

// ---------------------------------------------------------------------------
// Fused GRU, col-split 8, XCD-aware persistent grid; pipelined A- AND hv-loads.
// ---------------------------------------------------------------------------
__global__ __launch_bounds__(256) void gru_fused(const unsigned short* __restrict__ Agg,
                                                 const unsigned short* __restrict__ Hin,
                                                 unsigned short* __restrict__ Hout,
                                                 const unsigned short* __restrict__ Wih,
                                                 const unsigned short* __restrict__ Whh,
                                                 const float* __restrict__ bih,
                                                 const float* __restrict__ bhh) {
    int cg, rb;
    cell_decode(blockIdx.x, cg, rb);
    __shared__ unsigned short lds[24 * 512];   // 24 KB
    const int lane = threadIdx.x & 63, wave = threadIdx.x >> 6;
    const int rl = lane & 15, kg = lane >> 4;
    const int col0 = cg * 16;
    for (int q = wave; q < 24; q += 4) {
        int s = q >> 2, kk = q & 3;
        const unsigned short* src = (s < 3 ? Wih + (size_t)s * 128 * KD
                                           : Whh + (size_t)(s - 3) * 128 * KD)
                                    + (size_t)(col0 + rl) * KD + kk * 32 + kg * 8;
        stage_frag(src, lds + q * 512);
    }
    __syncthreads();
    const int col = col0 + rl;
    const float b_ir = bih[col], b_iz = bih[128 + col], b_in = bih[256 + col];
    const float b_hr = bhh[col], b_hz = bhh[128 + col], b_hn = bhh[256 + col];
    int rt = rb * 4 + wave;
    if (rt >= RT_TILES) return;
    bf16x8 a1[4], a2[4];
    unsigned short hvc[4];
#pragma unroll
    for (int kk = 0; kk < 4; ++kk) {
        a1[kk] = ldfrag(Agg + ((size_t)rt * 16 + rl) * KD + kk * 32 + kg * 8);
        a2[kk] = ldfrag(Hin + ((size_t)rt * 16 + rl) * KD + kk * 32 + kg * 8);
    }
#pragma unroll
    for (int p = 0; p < 4; ++p)
        hvc[p] = Hin[(size_t)(rt * 16 + kg * 4 + p) * KD + col];
    while (rt < RT_TILES) {
        const int rtn = rt + CELL_STRIDE;
        bf16x8 n1[4], n2[4];
        unsigned short hvn[4];
        if (rtn < RT_TILES) {
#pragma unroll
            for (int kk = 0; kk < 4; ++kk) {
                n1[kk] = ldfrag(Agg + ((size_t)rtn * 16 + rl) * KD + kk * 32 + kg * 8);
                n2[kk] = ldfrag(Hin + ((size_t)rtn * 16 + rl) * KD + kk * 32 + kg * 8);
            }
#pragma unroll
            for (int p = 0; p < 4; ++p)
                hvn[p] = Hin[(size_t)(rtn * 16 + kg * 4 + p) * KD + col];
        }
        f32x4 ir = {0.f,0.f,0.f,0.f}, iz = ir, in_ = ir, hr = ir, hz = ir, hn = ir;
#pragma unroll
        for (int kk = 0; kk < 4; ++kk) {
            ir  = __builtin_amdgcn_mfma_f32_16x16x32_bf16(a1[kk], ldfrag(lds + (0*4+kk)*512 + lane*8), ir,  0, 0, 0);
            iz  = __builtin_amdgcn_mfma_f32_16x16x32_bf16(a1[kk], ldfrag(lds + (1*4+kk)*512 + lane*8), iz,  0, 0, 0);
            in_ = __builtin_amdgcn_mfma_f32_16x16x32_bf16(a1[kk], ldfrag(lds + (2*4+kk)*512 + lane*8), in_, 0, 0, 0);
            hr  = __builtin_amdgcn_mfma_f32_16x16x32_bf16(a2[kk], ldfrag(lds + (3*4+kk)*512 + lane*8), hr,  0, 0, 0);
            hz  = __builtin_amdgcn_mfma_f32_16x16x32_bf16(a2[kk], ldfrag(lds + (4*4+kk)*512 + lane*8), hz,  0, 0, 0);
            hn  = __builtin_amdgcn_mfma_f32_16x16x32_bf16(a2[kk], ldfrag(lds + (5*4+kk)*512 + lane*8), hn,  0, 0, 0);
        }
#pragma unroll
        for (int p = 0; p < 4; ++p) {
            int row = rt * 16 + kg * 4 + p;
            float r = fsig(ir[p] + b_ir + hr[p] + b_hr);
            float z = fsig(iz[p] + b_iz + hz[p] + b_hz);
            float nc = ftanh(in_[p] + b_in + r * (hn[p] + b_hn));
            float hv = bf2f(hvc[p]);
            Hout[(size_t)row * KD + col] = f2bf((1.f - z) * nc + z * hv);
        }
        rt = rtn;
#pragma unroll
        for (int kk = 0; kk < 4; ++kk) { a1[kk] = n1[kk]; a2[kk] = n2[kk]; }
#pragma unroll
        for (int p = 0; p < 4; ++p) hvc[p] = hvn[p];
    }
}

// ---------------------------------------------------------------------------
// Fused LSTM, col-split 8, XCD-aware persistent grid; pipelined A/Cx loads.
// ---------------------------------------------------------------------------
__global__ __launch_bounds__(256) void lstm_fused(const unsigned short* __restrict__ Hh,
                                                  const unsigned short* __restrict__ Hx,
                                                  const float* __restrict__ Cx,
                                                  const unsigned short* __restrict__ Wih,
                                                  const unsigned short* __restrict__ Whh,
                                                  const float* __restrict__ bih,
                                                  const float* __restrict__ bhh,
                                                  float* __restrict__ h_out,
                                                  float* __restrict__ c_out,
                                                  unsigned short* __restrict__ Hrelu) {
    int cg, rb;
    cell_decode(blockIdx.x, cg, rb);
    __shared__ unsigned short lds[32 * 512];   // 32 KB
    const int lane = threadIdx.x & 63, wave = threadIdx.x >> 6;
    const int rl = lane & 15, kg = lane >> 4;
    const int col0 = cg * 16;
    for (int q = wave; q < 32; q += 4) {
        int s = q >> 2, kk = q & 3;
        const unsigned short* src = (s < 4 ? Wih + (size_t)s * 128 * KD
                                           : Whh + (size_t)(s - 4) * 128 * KD)
                                    + (size_t)(col0 + rl) * KD + kk * 32 + kg * 8;
        stage_frag(src, lds + q * 512);
    }
    __syncthreads();
    const int col = col0 + rl;
    const float b_i = bih[col] + bhh[col];
    const float b_f = bih[128 + col] + bhh[128 + col];
    const float b_g = bih[256 + col] + bhh[256 + col];
    const float b_o = bih[384 + col] + bhh[384 + col];
    int rt = rb * 4 + wave;
    if (rt >= RT_TILES) return;
    bf16x8 a1[4], a2[4];
    float cpre[4];
#pragma unroll
    for (int kk = 0; kk < 4; ++kk) {
        a1[kk] = ldfrag(Hh + ((size_t)rt * 16 + rl) * KD + kk * 32 + kg * 8);
        a2[kk] = ldfrag(Hx + ((size_t)rt * 16 + rl) * KD + kk * 32 + kg * 8);
    }
#pragma unroll
    for (int p = 0; p < 4; ++p)
        cpre[p] = Cx[(size_t)(rt * 16 + kg * 4 + p) * KD + col];
    while (rt < RT_TILES) {
        const int rtn = rt + CELL_STRIDE;
        bf16x8 n1[4], n2[4];
        float cnx[4];
        if (rtn < RT_TILES) {
#pragma unroll
            for (int kk = 0; kk < 4; ++kk) {
                n1[kk] = ldfrag(Hh + ((size_t)rtn * 16 + rl) * KD + kk * 32 + kg * 8);
                n2[kk] = ldfrag(Hx + ((size_t)rtn * 16 + rl) * KD + kk * 32 + kg * 8);
            }
#pragma unroll
            for (int p = 0; p < 4; ++p)
                cnx[p] = Cx[(size_t)(rtn * 16 + kg * 4 + p) * KD + col];
        }
        f32x4 gi = {0.f,0.f,0.f,0.f}, gf = gi, gg = gi, go = gi;
        f32x4 hi = gi, hf = gi, hg = gi, ho = gi;
#pragma unroll
        for (int kk = 0; kk < 4; ++kk) {
            gi = __builtin_amdgcn_mfma_f32_16x16x32_bf16(a1[kk], ldfrag(lds + (0*4+kk)*512 + lane*8), gi, 0, 0, 0);
            gf = __builtin_amdgcn_mfma_f32_16x16x32_bf16(a1[kk], ldfrag(lds + (1*4+kk)*512 + lane*8), gf, 0, 0, 0);
            gg = __builtin_amdgcn_mfma_f32_16x16x32_bf16(a1[kk], ldfrag(lds + (2*4+kk)*512 + lane*8), gg, 0, 0, 0);
            go = __builtin_amdgcn_mfma_f32_16x16x32_bf16(a1[kk], ldfrag(lds + (3*4+kk)*512 + lane*8), go, 0, 0, 0);
            hi = __builtin_amdgcn_mfma_f32_16x16x32_bf16(a2[kk], ldfrag(lds + (4*4+kk)*512 + lane*8), hi, 0, 0, 0);
            hf = __builtin_amdgcn_mfma_f32_16x16x32_bf16(a2[kk], ldfrag(lds + (5*4+kk)*512 + lane*8), hf, 0, 0, 0);
            hg = __builtin_amdgcn_mfma_f32_16x16x32_bf16(a2[kk], ldfrag(lds + (6*4+kk)*512 + lane*8), hg, 0, 0, 0);
            ho = __builtin_amdgcn_mfma_f32_16x16x32_bf16(a2[kk], ldfrag(lds + (7*4+kk)*512 + lane*8), ho, 0, 0, 0);
        }
#pragma unroll
        for (int p = 0; p < 4; ++p) {
            int row = rt * 16 + kg * 4 + p;
            size_t idx = (size_t)row * KD + col;
            float ig = fsig(gi[p] + hi[p] + b_i);
            float fg = fsig(gf[p] + hf[p] + b_f);
            float gv = ftanh(gg[p] + hg[p] + b_g);
            float og = fsig(go[p] + ho[p] + b_o);
            float c = fg * cpre[p] + ig * gv;
            float hn = og * ftanh(c);
            c_out[idx] = c;
            h_out[idx] = hn;
            Hrelu[idx] = f2bf(fmaxf(hn, 0.f));
        }
        rt = rtn;
#pragma unroll
        for (int kk = 0; kk < 4; ++kk) { a1[kk] = n1[kk]; a2[kk] = n2[kk]; }
#pragma unroll
        for (int p = 0; p < 4; ++p) cpre[p] = cnx[p];
    }
}

// ---------------------------------------------------------------------------
// head: out[N][64] = hrelu @ lin_wᵀ + lin_b; pipelined row-stride.
// ---------------------------------------------------------------------------
__global__ __launch_bounds__(256) void head_gemm(const unsigned short* __restrict__ Hr,
                                                 const unsigned short* __restrict__ LinW,
                                                 const float* __restrict__ lin_b,
                                                 float* __restrict__ Out) {
    __shared__ unsigned short wlds[16 * 512];
    const int lane = threadIdx.x & 63, wave = threadIdx.x >> 6;
    const int rl = lane & 15, kg = lane >> 4;
    for (int f = wave; f < 16; f += 4) {
        int jt = f >> 2, kk = f & 3;
        stage_frag(LinW + (size_t)(jt * 16 + rl) * KD + kk * 32 + kg * 8, wlds + f * 512);
    }
    __syncthreads();
    const int stride = gridDim.x << 2;
    int rt = blockIdx.x * 4 + wave;
    if (rt >= RT_TILES) return;
    bf16x8 a[4];
#pragma unroll
    for (int kk = 0; kk < 4; ++kk)
        a[kk] = ldfrag(Hr + ((size_t)rt * 16 + rl) * KD + kk * 32 + kg * 8);
    while (rt < RT_TILES) {
        const int rtn = rt + stride;
        bf16x8 an[4];
        if (rtn < RT_TILES) {
#pragma unroll
            for (int kk = 0; kk < 4; ++kk)
                an[kk] = ldfrag(Hr + ((size_t)rtn * 16 + rl) * KD + kk * 32 + kg * 8);
        }
#pragma unroll
        for (int jt = 0; jt < 4; ++jt) {
            f32x4 acc = {0.f, 0.f, 0.f, 0.f};
#pragma unroll
            for (int kk = 0; kk < 4; ++kk)
                acc = __builtin_amdgcn_mfma_f32_16x16x32_bf16(
                    a[kk], ldfrag(wlds + (jt * 4 + kk) * 512 + lane * 8), acc, 0, 0, 0);
            int col = jt * 16 + rl;
            float b = lin_b[col];
#pragma unroll
            for (int p = 0; p < 4; ++p)
                Out[(size_t)(rt * 16 + kg * 4 + p) * 64 + col] = acc[p] + b;
        }
        rt = rtn;
#pragma unroll
        for (int kk = 0; kk < 4; ++kk) a[kk] = an[kk];
    }
}

extern "C" void kernel_launch(void* const* d_in, const int* in_sizes, int n_in,
                              void* d_out, int out_size, void* d_ws, size_t ws_size,
                              hipStream_t stream) {
    const float* x        = (const float*)d_in[0];
    const int*   ei       = (const int*)d_in[1];
    const float* ew       = (const float*)d_in[2];
    const float* H        = (const float*)d_in[3];
    const float* C        = (const float*)d_in[4];
    const float* ggc_w    = (const float*)d_in[5];
    const float* gru_wih  = (const float*)d_in[6];
    const float* gru_whh  = (const float*)d_in[7];
    const float* gru_bih  = (const float*)d_in[8];
    const float* gru_bhh  = (const float*)d_in[9];
    const float* lstm_wih = (const float*)d_in[10];
    const float* lstm_whh = (const float*)d_in[11];
    const float* lstm_bih = (const float*)d_in[12];
    const float* lstm_bhh = (const float*)d_in[13];
    const float* lin_w    = (const float*)d_in[14];
    const float* lin_b    = (const float*)d_in[15];

    float* out_head = (float*)d_out;
    float* h_out = out_head + (size_t)N_NODES * 64;
    float* c_out = h_out + (size_t)N_NODES * KD;

    char* w = (char*)d_ws;
    unsigned short* hb    = (unsigned short*)w; w += (size_t)N_NODES * KD * 2;
    unsigned short* hb1   = (unsigned short*)w; w += (size_t)N_NODES * KD * 2;
    unsigned short* Hxb   = (unsigned short*)w; w += (size_t)N_NODES * KD * 2;
    unsigned short* mb    = (unsigned short*)w; w += (size_t)N_NODES * KD * 2;  // Hrelu
    unsigned short* aggb  = (unsigned short*)w; w += (size_t)N_NODES * KD * 2;  // gathered h
    unsigned short* WfT   = (unsigned short*)w; w += 2 * 384 * KD * 2;          // fused Wg·Wih^T
    unsigned short* whhb  = (unsigned short*)w; w += 384 * KD * 2;
    unsigned short* lwihb = (unsigned short*)w; w += 512 * KD * 2;
    unsigned short* lwhhb = (unsigned short*)w; w += 512 * KD * 2;
    unsigned short* linwb = (unsigned short*)w; w += 64 * KD * 2;
    int*   rowptr = (int*)w; w += 50304 * 4;
    int*   cursor = (int*)w; w += 50304 * 4;
    int*   bsum   = (int*)w; w += 256 * 4;
    int*   sSrc   = (int*)w; w += (size_t)E_EDGES * 4;
    float* sW     = (float*)w; w += (size_t)E_EDGES * 4;

    dim3 blk(256);
    const int EB = (E_EDGES + 255) / 256;
    const int NF4 = N_NODES * KD / 4;

    cvt_xh<<<(2 * NF4 + 255) / 256, blk, 0, stream>>>(x, H, hb, Hxb, NF4);
    cvt_weights<<<(47104 + 255) / 256, blk, 0, stream>>>(
        gru_whh, lstm_wih, lstm_whh, lin_w,
        whhb, lwihb, lwhhb, linwb);
    fuse_wg_wih<<<dim3(384, 2), 128, 0, stream>>>(ggc_w, gru_wih, WfT);

    hipMemsetAsync(cursor, 0, N_NODES * sizeof(int), stream);
    count_deg<<<EB, blk, 0, stream>>>(ei, cursor);
    scan_p1<<<NBLK_SCAN, blk, 0, stream>>>(cursor, rowptr, bsum);
    scan_p2<<<1, blk, 0, stream>>>(bsum, rowptr + N_NODES);
    scan_p3<<<NBLK_SCAN, blk, 0, stream>>>(bsum, rowptr, cursor);
    fill_csr<<<EB, blk, 0, stream>>>(ei, ew, cursor, sSrc, sW);

    // layer 0
    gather_agg_bf16<<<(N_NODES * 64 + 255) / 256, blk, 0, stream>>>(
        hb, rowptr, sSrc, sW, aggb);
    gru_fused<<<CELL_BLOCKS, blk, 0, stream>>>(aggb, hb, hb1,
                                               WfT, whhb, gru_bih, gru_bhh);
    // layer 1
    gather_agg_bf16<<<(N_NODES * 64 + 255) / 256, blk, 0, stream>>>(
        hb1, rowptr, sSrc, sW, aggb);
    gru_fused<<<CELL_BLOCKS, blk, 0, stream>>>(aggb, hb1, hb,
                                               WfT + (size_t)384 * KD, whhb, gru_bih, gru_bhh);

    lstm_fused<<<CELL_BLOCKS, blk, 0, stream>>>(hb, Hxb, C, lwihb, lwhhb,
                                                lstm_bih, lstm_bhh, h_out, c_out, mb);
    head_gemm<<<391, blk, 0, stream>>>(mb, linwb, lin_b, out_head);
}

// Round 13
// 310.264 us; speedup vs baseline: 1.2911x; 1.0064x over previous
//
#include <hip/hip_runtime.h>
#include <math.h>

#define N_NODES 50000
#define E_EDGES 800000
#define KD 128
#define NBLK_SCAN 196   // ceil(50000/256)
#define RT_TILES 3125   // N_NODES / 16 (exact)
#define CELL_RB 128     // rowblocks in cell kernels (persistent: 4 blocks/CU)
#define CELL_STRIDE (CELL_RB * 4)
#define CELL_BLOCKS 1024

typedef __attribute__((ext_vector_type(8))) short bf16x8;
typedef __attribute__((ext_vector_type(4))) float f32x4;

__device__ __forceinline__ float fsig(float x) { return 1.f / (1.f + __expf(-x)); }
__device__ __forceinline__ float ftanh(float x) { return 1.f - 2.f / (1.f + __expf(2.f * x)); }

__device__ __forceinline__ unsigned short f2bf(float f) {
    unsigned u = __float_as_uint(f);
    return (unsigned short)((u + 0x7FFFu + ((u >> 16) & 1u)) >> 16);
}
__device__ __forceinline__ float bf2f(unsigned short b) {
    return __uint_as_float(((unsigned)b) << 16);
}
__device__ __forceinline__ bf16x8 ldfrag(const unsigned short* p) {
    return *(const bf16x8*)(const void*)p;
}
__device__ __forceinline__ void stage_frag(const unsigned short* g, unsigned short* l) {
    __builtin_amdgcn_global_load_lds(
        (const __attribute__((address_space(1))) unsigned int*)g,
        (__attribute__((address_space(3))) unsigned int*)l, 16, 0, 0);
}
// XCD-aware decode: 8 colgroup-sharers of a rowblock get ids spaced 8 apart
// (same id%8 -> same XCD, co-resident). [R9 measured: FETCH 125 -> 26.8 MB]
// 1024 blocks = 128 rowblocks x 8 colgroups, exactly 4 blocks/CU resident.
__device__ __forceinline__ void cell_decode(int id, int& x, int& y) {
    y = ((id >> 6) << 3) + (id & 7);   // rowblock 0..127
    x = (id >> 3) & 7;                 // colgroup 0..7
}

// ---------------------------------------------------------------------------
// fp32 -> bf16 converts
// ---------------------------------------------------------------------------
__global__ __launch_bounds__(256) void cvt_xh(const float* __restrict__ x,
                                              const float* __restrict__ H,
                                              unsigned short* __restrict__ hb,
                                              unsigned short* __restrict__ Hxb, int n4) {
    int t = blockIdx.x * 256 + threadIdx.x;
    const float* in; unsigned short* out; int idx;
    if (t < n4) { in = x; out = hb; idx = t; }
    else if (t < 2 * n4) { in = H; out = Hxb; idx = t - n4; }
    else return;
    float4 v = ((const float4*)in)[idx];
    ushort4 o;
    o.x = f2bf(v.x); o.y = f2bf(v.y); o.z = f2bf(v.z); o.w = f2bf(v.w);
    ((ushort4*)out)[idx] = o;
}

__global__ __launch_bounds__(256) void cvt_weights(
        const float* __restrict__ b,
        const float* __restrict__ c, const float* __restrict__ d,
        const float* __restrict__ e,
        unsigned short* __restrict__ ob,
        unsigned short* __restrict__ oc, unsigned short* __restrict__ od,
        unsigned short* __restrict__ oe) {
    int t = blockIdx.x * 256 + threadIdx.x;
    const float* in; unsigned short* out; int idx;
    if      (t < 12288)  { in = b; out = ob; idx = t; }            // gru_whh
    else if (t < 28672)  { in = c; out = oc; idx = t - 12288; }    // lstm_wih
    else if (t < 45056)  { in = d; out = od; idx = t - 28672; }    // lstm_whh
    else if (t < 47104)  { in = e; out = oe; idx = t - 45056; }    // lin_w
    else return;
    float4 v = ((const float4*)in)[idx];
    ushort4 o;
    o.x = f2bf(v.x); o.y = f2bf(v.y); o.z = f2bf(v.z); o.w = f2bf(v.w);
    ((ushort4*)out)[idx] = o;
}

// ---------------------------------------------------------------------------
// Fused GGC+GRU-input weight: WfT[l][j][k] = sum_c Wg[l][k][c] * Wih[j][c]
// ---------------------------------------------------------------------------
__global__ __launch_bounds__(128) void fuse_wg_wih(const float* __restrict__ Wg,
                                                   const float* __restrict__ Wih,
                                                   unsigned short* __restrict__ WfT) {
    __shared__ float wi[128];
    const int j = blockIdx.x;
    const int l = blockIdx.y;
    const int k = threadIdx.x;
    wi[k] = Wih[j * 128 + k];
    __syncthreads();
    const float* wg = Wg + l * 16384 + k * 128;
    float s = 0.f;
#pragma unroll 8
    for (int c = 0; c < 128; c += 4) {
        float4 a = *(const float4*)(wg + c);
        s += a.x * wi[c] + a.y * wi[c + 1] + a.z * wi[c + 2] + a.w * wi[c + 3];
    }
    WfT[((size_t)l * 384 + j) * 128 + k] = f2bf(s);
}

// ---------------------------------------------------------------------------
// CSR build
// ---------------------------------------------------------------------------
__global__ __launch_bounds__(256) void count_deg(const int* __restrict__ ei,
                                                 int* __restrict__ deg) {
    int e = blockIdx.x * 256 + threadIdx.x;
    if (e >= E_EDGES) return;
    atomicAdd(&deg[ei[E_EDGES + e]], 1);
}

__global__ __launch_bounds__(256) void scan_p1(const int* __restrict__ deg,
                                               int* __restrict__ excl,
                                               int* __restrict__ bsum) {
    __shared__ int part[256];
    const int t = threadIdx.x;
    const int i = blockIdx.x * 256 + t;
    int v = (i < N_NODES) ? deg[i] : 0;
    part[t] = v;
    __syncthreads();
#pragma unroll
    for (int off = 1; off < 256; off <<= 1) {
        int u = (t >= off) ? part[t - off] : 0;
        __syncthreads();
        part[t] += u;
        __syncthreads();
    }
    if (i < N_NODES) excl[i] = part[t] - v;
    if (t == 255) bsum[blockIdx.x] = part[255];
}

__global__ __launch_bounds__(256) void scan_p2(int* __restrict__ bsum,
                                               int* __restrict__ rowptrN) {
    __shared__ int part[256];
    const int t = threadIdx.x;
    int v = (t < NBLK_SCAN) ? bsum[t] : 0;
    part[t] = v;
    __syncthreads();
#pragma unroll
    for (int off = 1; off < 256; off <<= 1) {
        int u = (t >= off) ? part[t - off] : 0;
        __syncthreads();
        part[t] += u;
        __syncthreads();
    }
    if (t < NBLK_SCAN) bsum[t] = part[t] - v;
    if (t == 255) *rowptrN = part[255];
}

__global__ __launch_bounds__(256) void scan_p3(const int* __restrict__ bsum,
                                               int* __restrict__ rowptr,
                                               int* __restrict__ cursor) {
    int i = blockIdx.x * 256 + threadIdx.x;
    if (i >= N_NODES) return;
    int r = rowptr[i] + bsum[blockIdx.x];
    rowptr[i] = r;
    cursor[i] = r;
}

// Packed fill: one 8B store per edge (src, weight) -> halves dirty-line count
__global__ __launch_bounds__(256) void fill_csr(const int* __restrict__ ei,
                                                const float* __restrict__ ew,
                                                int* __restrict__ cursor,
                                                int2* __restrict__ sEdge) {
    int e = blockIdx.x * 256 + threadIdx.x;
    if (e >= E_EDGES) return;
    int dst = ei[E_EDGES + e];
    int pos = atomicAdd(&cursor[dst], 1);
    int2 pk;
    pk.x = ei[e];
    pk.y = __float_as_int(ew[e]);
    sEdge[pos] = pk;
}

// ---------------------------------------------------------------------------
// gh[n,:] = sum_e w[e]*h[src[e],:]; one node/wave, packed-edge prefetch
// ---------------------------------------------------------------------------
__global__ __launch_bounds__(256) void gather_agg_bf16(const unsigned short* __restrict__ m,
                                                       const int* __restrict__ rowptr,
                                                       const int2* __restrict__ sEdge,
                                                       unsigned short* __restrict__ agg) {
    int wid = (blockIdx.x * 256 + threadIdx.x) >> 6;
    if (wid >= N_NODES) return;
    int lane = threadIdx.x & 63;
    int half = lane >> 5, li = lane & 31;
    int f0 = li << 2;
    int e0 = rowptr[wid], e1 = rowptr[wid + 1];
    float ax = 0.f, ay = 0.f, az = 0.f, aw = 0.f;
    int e = e0 + half;
    int2 pk_nx = make_int2(0, 0);
    if (e < e1) pk_nx = sEdge[e];
    for (; e < e1; e += 2) {
        int s = pk_nx.x;
        float ww = __int_as_float(pk_nx.y);
        int en = e + 2;
        if (en < e1) pk_nx = sEdge[en];
        ushort4 v = *(const ushort4*)(m + (size_t)s * KD + f0);
        ax += ww * bf2f(v.x); ay += ww * bf2f(v.y);
        az += ww * bf2f(v.z); aw += ww * bf2f(v.w);
    }
    ax += __shfl_xor(ax, 32, 64);
    ay += __shfl_xor(ay, 32, 64);
    az += __shfl_xor(az, 32, 64);
    aw += __shfl_xor(aw, 32, 64);
    if (half == 0) {
        ushort4 o;
        o.x = f2bf(ax); o.y = f2bf(ay); o.z = f2bf(az); o.w = f2bf(aw);
        *(ushort4*)(agg + (size_t)wid * KD + f0) = o;
    }
}

// ---------------------------------------------------------------------------
// Fused GRU, col-split 8, XCD-aware persistent grid; pipelined A- AND hv-loads.
// ---------------------------------------------------------------------------
__global__ __launch_bounds__(256) void gru_fused(const unsigned short* __restrict__ Agg,
                                                 const unsigned short* __restrict__ Hin,
                                                 unsigned short* __restrict__ Hout,
                                                 const unsigned short* __restrict__ Wih,
                                                 const unsigned short* __restrict__ Whh,
                                                 const float* __restrict__ bih,
                                                 const float* __restrict__ bhh) {
    int cg, rb;
    cell_decode(blockIdx.x, cg, rb);
    __shared__ unsigned short lds[24 * 512];   // 24 KB
    const int lane = threadIdx.x & 63, wave = threadIdx.x >> 6;
    const int rl = lane & 15, kg = lane >> 4;
    const int col0 = cg * 16;
    for (int q = wave; q < 24; q += 4) {
        int s = q >> 2, kk = q & 3;
        const unsigned short* src = (s < 3 ? Wih + (size_t)s * 128 * KD
                                           : Whh + (size_t)(s - 3) * 128 * KD)
                                    + (size_t)(col0 + rl) * KD + kk * 32 + kg * 8;
        stage_frag(src, lds + q * 512);
    }
    __syncthreads();
    const int col = col0 + rl;
    const float b_ir = bih[col], b_iz = bih[128 + col], b_in = bih[256 + col];
    const float b_hr = bhh[col], b_hz = bhh[128 + col], b_hn = bhh[256 + col];
    int rt = rb * 4 + wave;
    if (rt >= RT_TILES) return;
    bf16x8 a1[4], a2[4];
    unsigned short hvc[4];
#pragma unroll
    for (int kk = 0; kk < 4; ++kk) {
        a1[kk] = ldfrag(Agg + ((size_t)rt * 16 + rl) * KD + kk * 32 + kg * 8);
        a2[kk] = ldfrag(Hin + ((size_t)rt * 16 + rl) * KD + kk * 32 + kg * 8);
    }
#pragma unroll
    for (int p = 0; p < 4; ++p)
        hvc[p] = Hin[(size_t)(rt * 16 + kg * 4 + p) * KD + col];
    while (rt < RT_TILES) {
        const int rtn = rt + CELL_STRIDE;
        bf16x8 n1[4], n2[4];
        unsigned short hvn[4];
        if (rtn < RT_TILES) {
#pragma unroll
            for (int kk = 0; kk < 4; ++kk) {
                n1[kk] = ldfrag(Agg + ((size_t)rtn * 16 + rl) * KD + kk * 32 + kg * 8);
                n2[kk] = ldfrag(Hin + ((size_t)rtn * 16 + rl) * KD + kk * 32 + kg * 8);
            }
#pragma unroll
            for (int p = 0; p < 4; ++p)
                hvn[p] = Hin[(size_t)(rtn * 16 + kg * 4 + p) * KD + col];
        }
        f32x4 ir = {0.f,0.f,0.f,0.f}, iz = ir, in_ = ir, hr = ir, hz = ir, hn = ir;
#pragma unroll
        for (int kk = 0; kk < 4; ++kk) {
            ir  = __builtin_amdgcn_mfma_f32_16x16x32_bf16(a1[kk], ldfrag(lds + (0*4+kk)*512 + lane*8), ir,  0, 0, 0);
            iz  = __builtin_amdgcn_mfma_f32_16x16x32_bf16(a1[kk], ldfrag(lds + (1*4+kk)*512 + lane*8), iz,  0, 0, 0);
            in_ = __builtin_amdgcn_mfma_f32_16x16x32_bf16(a1[kk], ldfrag(lds + (2*4+kk)*512 + lane*8), in_, 0, 0, 0);
            hr  = __builtin_amdgcn_mfma_f32_16x16x32_bf16(a2[kk], ldfrag(lds + (3*4+kk)*512 + lane*8), hr,  0, 0, 0);
            hz  = __builtin_amdgcn_mfma_f32_16x16x32_bf16(a2[kk], ldfrag(lds + (4*4+kk)*512 + lane*8), hz,  0, 0, 0);
            hn  = __builtin_amdgcn_mfma_f32_16x16x32_bf16(a2[kk], ldfrag(lds + (5*4+kk)*512 + lane*8), hn,  0, 0, 0);
        }
#pragma unroll
        for (int p = 0; p < 4; ++p) {
            int row = rt * 16 + kg * 4 + p;
            float r = fsig(ir[p] + b_ir + hr[p] + b_hr);
            float z = fsig(iz[p] + b_iz + hz[p] + b_hz);
            float nc = ftanh(in_[p] + b_in + r * (hn[p] + b_hn));
            float hv = bf2f(hvc[p]);
            Hout[(size_t)row * KD + col] = f2bf((1.f - z) * nc + z * hv);
        }
        rt = rtn;
#pragma unroll
        for (int kk = 0; kk < 4; ++kk) { a1[kk] = n1[kk]; a2[kk] = n2[kk]; }
#pragma unroll
        for (int p = 0; p < 4; ++p) hvc[p] = hvn[p];
    }
}

// ---------------------------------------------------------------------------
// Fused LSTM, col-split 8, XCD-aware persistent grid; pipelined A/Cx loads.
// ---------------------------------------------------------------------------
__global__ __launch_bounds__(256) void lstm_fused(const unsigned short* __restrict__ Hh,
                                                  const unsigned short* __restrict__ Hx,
                                                  const float* __restrict__ Cx,
                                                  const unsigned short* __restrict__ Wih,
                                                  const unsigned short* __restrict__ Whh,
                                                  const float* __restrict__ bih,
                                                  const float* __restrict__ bhh,
                                                  float* __restrict__ h_out,
                                                  float* __restrict__ c_out,
                                                  unsigned short* __restrict__ Hrelu) {
    int cg, rb;
    cell_decode(blockIdx.x, cg, rb);
    __shared__ unsigned short lds[32 * 512];   // 32 KB
    const int lane = threadIdx.x & 63, wave = threadIdx.x >> 6;
    const int rl = lane & 15, kg = lane >> 4;
    const int col0 = cg * 16;
    for (int q = wave; q < 32; q += 4) {
        int s = q >> 2, kk = q & 3;
        const unsigned short* src = (s < 4 ? Wih + (size_t)s * 128 * KD
                                           : Whh + (size_t)(s - 4) * 128 * KD)
                                    + (size_t)(col0 + rl) * KD + kk * 32 + kg * 8;
        stage_frag(src, lds + q * 512);
    }
    __syncthreads();
    const int col = col0 + rl;
    const float b_i = bih[col] + bhh[col];
    const float b_f = bih[128 + col] + bhh[128 + col];
    const float b_g = bih[256 + col] + bhh[256 + col];
    const float b_o = bih[384 + col] + bhh[384 + col];
    int rt = rb * 4 + wave;
    if (rt >= RT_TILES) return;
    bf16x8 a1[4], a2[4];
    float cpre[4];
#pragma unroll
    for (int kk = 0; kk < 4; ++kk) {
        a1[kk] = ldfrag(Hh + ((size_t)rt * 16 + rl) * KD + kk * 32 + kg * 8);
        a2[kk] = ldfrag(Hx + ((size_t)rt * 16 + rl) * KD + kk * 32 + kg * 8);
    }
#pragma unroll
    for (int p = 0; p < 4; ++p)
        cpre[p] = Cx[(size_t)(rt * 16 + kg * 4 + p) * KD + col];
    while (rt < RT_TILES) {
        const int rtn = rt + CELL_STRIDE;
        bf16x8 n1[4], n2[4];
        float cnx[4];
        if (rtn < RT_TILES) {
#pragma unroll
            for (int kk = 0; kk < 4; ++kk) {
                n1[kk] = ldfrag(Hh + ((size_t)rtn * 16 + rl) * KD + kk * 32 + kg * 8);
                n2[kk] = ldfrag(Hx + ((size_t)rtn * 16 + rl) * KD + kk * 32 + kg * 8);
            }
#pragma unroll
            for (int p = 0; p < 4; ++p)
                cnx[p] = Cx[(size_t)(rtn * 16 + kg * 4 + p) * KD + col];
        }
        f32x4 gi = {0.f,0.f,0.f,0.f}, gf = gi, gg = gi, go = gi;
        f32x4 hi = gi, hf = gi, hg = gi, ho = gi;
#pragma unroll
        for (int kk = 0; kk < 4; ++kk) {
            gi = __builtin_amdgcn_mfma_f32_16x16x32_bf16(a1[kk], ldfrag(lds + (0*4+kk)*512 + lane*8), gi, 0, 0, 0);
            gf = __builtin_amdgcn_mfma_f32_16x16x32_bf16(a1[kk], ldfrag(lds + (1*4+kk)*512 + lane*8), gf, 0, 0, 0);
            gg = __builtin_amdgcn_mfma_f32_16x16x32_bf16(a1[kk], ldfrag(lds + (2*4+kk)*512 + lane*8), gg, 0, 0, 0);
            go = __builtin_amdgcn_mfma_f32_16x16x32_bf16(a1[kk], ldfrag(lds + (3*4+kk)*512 + lane*8), go, 0, 0, 0);
            hi = __builtin_amdgcn_mfma_f32_16x16x32_bf16(a2[kk], ldfrag(lds + (4*4+kk)*512 + lane*8), hi, 0, 0, 0);
            hf = __builtin_amdgcn_mfma_f32_16x16x32_bf16(a2[kk], ldfrag(lds + (5*4+kk)*512 + lane*8), hf, 0, 0, 0);
            hg = __builtin_amdgcn_mfma_f32_16x16x32_bf16(a2[kk], ldfrag(lds + (6*4+kk)*512 + lane*8), hg, 0, 0, 0);
            ho = __builtin_amdgcn_mfma_f32_16x16x32_bf16(a2[kk], ldfrag(lds + (7*4+kk)*512 + lane*8), ho, 0, 0, 0);
        }
#pragma unroll
        for (int p = 0; p < 4; ++p) {
            int row = rt * 16 + kg * 4 + p;
            size_t idx = (size_t)row * KD + col;
            float ig = fsig(gi[p] + hi[p] + b_i);
            float fg = fsig(gf[p] + hf[p] + b_f);
            float gv = ftanh(gg[p] + hg[p] + b_g);
            float og = fsig(go[p] + ho[p] + b_o);
            float c = fg * cpre[p] + ig * gv;
            float hn = og * ftanh(c);
            c_out[idx] = c;
            h_out[idx] = hn;
            Hrelu[idx] = f2bf(fmaxf(hn, 0.f));
        }
        rt = rtn;
#pragma unroll
        for (int kk = 0; kk < 4; ++kk) { a1[kk] = n1[kk]; a2[kk] = n2[kk]; }
#pragma unroll
        for (int p = 0; p < 4; ++p) cpre[p] = cnx[p];
    }
}

// ---------------------------------------------------------------------------
// head: out[N][64] = hrelu @ lin_wᵀ + lin_b; pipelined row-stride.
// ---------------------------------------------------------------------------
__global__ __launch_bounds__(256) void head_gemm(const unsigned short* __restrict__ Hr,
                                                 const unsigned short* __restrict__ LinW,
                                                 const float* __restrict__ lin_b,
                                                 float* __restrict__ Out) {
    __shared__ unsigned short wlds[16 * 512];
    const int lane = threadIdx.x & 63, wave = threadIdx.x >> 6;
    const int rl = lane & 15, kg = lane >> 4;
    for (int f = wave; f < 16; f += 4) {
        int jt = f >> 2, kk = f & 3;
        stage_frag(LinW + (size_t)(jt * 16 + rl) * KD + kk * 32 + kg * 8, wlds + f * 512);
    }
    __syncthreads();
    const int stride = gridDim.x << 2;
    int rt = blockIdx.x * 4 + wave;
    if (rt >= RT_TILES) return;
    bf16x8 a[4];
#pragma unroll
    for (int kk = 0; kk < 4; ++kk)
        a[kk] = ldfrag(Hr + ((size_t)rt * 16 + rl) * KD + kk * 32 + kg * 8);
    while (rt < RT_TILES) {
        const int rtn = rt + stride;
        bf16x8 an[4];
        if (rtn < RT_TILES) {
#pragma unroll
            for (int kk = 0; kk < 4; ++kk)
                an[kk] = ldfrag(Hr + ((size_t)rtn * 16 + rl) * KD + kk * 32 + kg * 8);
        }
#pragma unroll
        for (int jt = 0; jt < 4; ++jt) {
            f32x4 acc = {0.f, 0.f, 0.f, 0.f};
#pragma unroll
            for (int kk = 0; kk < 4; ++kk)
                acc = __builtin_amdgcn_mfma_f32_16x16x32_bf16(
                    a[kk], ldfrag(wlds + (jt * 4 + kk) * 512 + lane * 8), acc, 0, 0, 0);
            int col = jt * 16 + rl;
            float b = lin_b[col];
#pragma unroll
            for (int p = 0; p < 4; ++p)
                Out[(size_t)(rt * 16 + kg * 4 + p) * 64 + col] = acc[p] + b;
        }
        rt = rtn;
#pragma unroll
        for (int kk = 0; kk < 4; ++kk) a[kk] = an[kk];
    }
}

extern "C" void kernel_launch(void* const* d_in, const int* in_sizes, int n_in,
                              void* d_out, int out_size, void* d_ws, size_t ws_size,
                              hipStream_t stream) {
    const float* x        = (const float*)d_in[0];
    const int*   ei       = (const int*)d_in[1];
    const float* ew       = (const float*)d_in[2];
    const float* H        = (const float*)d_in[3];
    const float* C        = (const float*)d_in[4];
    const float* ggc_w    = (const float*)d_in[5];
    const float* gru_wih  = (const float*)d_in[6];
    const float* gru_whh  = (const float*)d_in[7];
    const float* gru_bih  = (const float*)d_in[8];
    const float* gru_bhh  = (const float*)d_in[9];
    const float* lstm_wih = (const float*)d_in[10];
    const float* lstm_whh = (const float*)d_in[11];
    const float* lstm_bih = (const float*)d_in[12];
    const float* lstm_bhh = (const float*)d_in[13];
    const float* lin_w    = (const float*)d_in[14];
    const float* lin_b    = (const float*)d_in[15];

    float* out_head = (float*)d_out;
    float* h_out = out_head + (size_t)N_NODES * 64;
    float* c_out = h_out + (size_t)N_NODES * KD;

    char* w = (char*)d_ws;
    unsigned short* hb    = (unsigned short*)w; w += (size_t)N_NODES * KD * 2;
    unsigned short* hb1   = (unsigned short*)w; w += (size_t)N_NODES * KD * 2;
    unsigned short* Hxb   = (unsigned short*)w; w += (size_t)N_NODES * KD * 2;
    unsigned short* mb    = (unsigned short*)w; w += (size_t)N_NODES * KD * 2;  // Hrelu
    unsigned short* aggb  = (unsigned short*)w; w += (size_t)N_NODES * KD * 2;  // gathered h
    unsigned short* WfT   = (unsigned short*)w; w += 2 * 384 * KD * 2;          // fused Wg·Wih^T
    unsigned short* whhb  = (unsigned short*)w; w += 384 * KD * 2;
    unsigned short* lwihb = (unsigned short*)w; w += 512 * KD * 2;
    unsigned short* lwhhb = (unsigned short*)w; w += 512 * KD * 2;
    unsigned short* linwb = (unsigned short*)w; w += 64 * KD * 2;
    int*   rowptr = (int*)w; w += 50304 * 4;
    int*   cursor = (int*)w; w += 50304 * 4;
    int*   bsum   = (int*)w; w += 256 * 4;
    int2*  sEdge  = (int2*)w; w += (size_t)E_EDGES * 8;   // packed (src, weight)

    dim3 blk(256);
    const int EB = (E_EDGES + 255) / 256;
    const int NF4 = N_NODES * KD / 4;

    cvt_xh<<<(2 * NF4 + 255) / 256, blk, 0, stream>>>(x, H, hb, Hxb, NF4);
    cvt_weights<<<(47104 + 255) / 256, blk, 0, stream>>>(
        gru_whh, lstm_wih, lstm_whh, lin_w,
        whhb, lwihb, lwhhb, linwb);
    fuse_wg_wih<<<dim3(384, 2), 128, 0, stream>>>(ggc_w, gru_wih, WfT);

    hipMemsetAsync(cursor, 0, N_NODES * sizeof(int), stream);
    count_deg<<<EB, blk, 0, stream>>>(ei, cursor);
    scan_p1<<<NBLK_SCAN, blk, 0, stream>>>(cursor, rowptr, bsum);
    scan_p2<<<1, blk, 0, stream>>>(bsum, rowptr + N_NODES);
    scan_p3<<<NBLK_SCAN, blk, 0, stream>>>(bsum, rowptr, cursor);
    fill_csr<<<EB, blk, 0, stream>>>(ei, ew, cursor, sEdge);

    // layer 0
    gather_agg_bf16<<<(N_NODES * 64 + 255) / 256, blk, 0, stream>>>(
        hb, rowptr, sEdge, aggb);
    gru_fused<<<CELL_BLOCKS, blk, 0, stream>>>(aggb, hb, hb1,
                                               WfT, whhb, gru_bih, gru_bhh);
    // layer 1
    gather_agg_bf16<<<(N_NODES * 64 + 255) / 256, blk, 0, stream>>>(
        hb1, rowptr, sEdge, aggb);
    gru_fused<<<CELL_BLOCKS, blk, 0, stream>>>(aggb, hb1, hb,
                                               WfT + (size_t)384 * KD, whhb, gru_bih, gru_bhh);

    lstm_fused<<<CELL_BLOCKS, blk, 0, stream>>>(hb, Hxb, C, lwihb, lwhhb,
                                                lstm_bih, lstm_bhh, h_out, c_out, mb);
    head_gemm<<<391, blk, 0, stream>>>(mb, linwb, lin_b, out_head);
}

// Round 14
// 297.051 us; speedup vs baseline: 1.3485x; 1.0445x over previous
//
#include <hip/hip_runtime.h>
#include <math.h>

#define N_NODES 50000
#define E_EDGES 800000
#define KD 128
#define NBLK_SCAN 196   // ceil(50000/256)
#define RT_TILES 3125   // N_NODES / 16 (exact)
#define CELL_RB 128     // rowblocks in cell kernels (persistent: 4 blocks/CU)
#define CELL_STRIDE (CELL_RB * 4)
#define CELL_BLOCKS 1024

typedef __attribute__((ext_vector_type(8))) short bf16x8;
typedef __attribute__((ext_vector_type(4))) float f32x4;

__device__ __forceinline__ float fsig(float x) { return 1.f / (1.f + __expf(-x)); }
__device__ __forceinline__ float ftanh(float x) { return 1.f - 2.f / (1.f + __expf(2.f * x)); }

__device__ __forceinline__ unsigned short f2bf(float f) {
    unsigned u = __float_as_uint(f);
    return (unsigned short)((u + 0x7FFFu + ((u >> 16) & 1u)) >> 16);
}
__device__ __forceinline__ float bf2f(unsigned short b) {
    return __uint_as_float(((unsigned)b) << 16);
}
__device__ __forceinline__ bf16x8 ldfrag(const unsigned short* p) {
    return *(const bf16x8*)(const void*)p;
}
__device__ __forceinline__ void stage_frag(const unsigned short* g, unsigned short* l) {
    __builtin_amdgcn_global_load_lds(
        (const __attribute__((address_space(1))) unsigned int*)g,
        (__attribute__((address_space(3))) unsigned int*)l, 16, 0, 0);
}
// XCD-aware decode: 8 colgroup-sharers of a rowblock get ids spaced 8 apart
// (same id%8 -> same XCD, co-resident). [R9 measured: FETCH 125 -> 26.8 MB]
__device__ __forceinline__ void cell_decode(int id, int& x, int& y) {
    y = ((id >> 6) << 3) + (id & 7);   // rowblock 0..127
    x = (id >> 3) & 7;                 // colgroup 0..7
}

// ---------------------------------------------------------------------------
// fp32 -> bf16 converts
// ---------------------------------------------------------------------------
__global__ __launch_bounds__(256) void cvt_xh(const float* __restrict__ x,
                                              const float* __restrict__ H,
                                              unsigned short* __restrict__ hb,
                                              unsigned short* __restrict__ Hxb, int n4) {
    int t = blockIdx.x * 256 + threadIdx.x;
    const float* in; unsigned short* out; int idx;
    if (t < n4) { in = x; out = hb; idx = t; }
    else if (t < 2 * n4) { in = H; out = Hxb; idx = t - n4; }
    else return;
    float4 v = ((const float4*)in)[idx];
    ushort4 o;
    o.x = f2bf(v.x); o.y = f2bf(v.y); o.z = f2bf(v.z); o.w = f2bf(v.w);
    ((ushort4*)out)[idx] = o;
}

__global__ __launch_bounds__(256) void cvt_weights(
        const float* __restrict__ b,
        const float* __restrict__ c, const float* __restrict__ d,
        const float* __restrict__ e,
        unsigned short* __restrict__ ob,
        unsigned short* __restrict__ oc, unsigned short* __restrict__ od,
        unsigned short* __restrict__ oe) {
    int t = blockIdx.x * 256 + threadIdx.x;
    const float* in; unsigned short* out; int idx;
    if      (t < 12288)  { in = b; out = ob; idx = t; }            // gru_whh
    else if (t < 28672)  { in = c; out = oc; idx = t - 12288; }    // lstm_wih
    else if (t < 45056)  { in = d; out = od; idx = t - 28672; }    // lstm_whh
    else if (t < 47104)  { in = e; out = oe; idx = t - 45056; }    // lin_w
    else return;
    float4 v = ((const float4*)in)[idx];
    ushort4 o;
    o.x = f2bf(v.x); o.y = f2bf(v.y); o.z = f2bf(v.z); o.w = f2bf(v.w);
    ((ushort4*)out)[idx] = o;
}

// ---------------------------------------------------------------------------
// Fused GGC+GRU-input weight: WfT[l][j][k] = sum_c Wg[l][k][c] * Wih[j][c]
// ---------------------------------------------------------------------------
__global__ __launch_bounds__(128) void fuse_wg_wih(const float* __restrict__ Wg,
                                                   const float* __restrict__ Wih,
                                                   unsigned short* __restrict__ WfT) {
    __shared__ float wi[128];
    const int j = blockIdx.x;
    const int l = blockIdx.y;
    const int k = threadIdx.x;
    wi[k] = Wih[j * 128 + k];
    __syncthreads();
    const float* wg = Wg + l * 16384 + k * 128;
    float s = 0.f;
#pragma unroll 8
    for (int c = 0; c < 128; c += 4) {
        float4 a = *(const float4*)(wg + c);
        s += a.x * wi[c] + a.y * wi[c + 1] + a.z * wi[c + 2] + a.w * wi[c + 3];
    }
    WfT[((size_t)l * 384 + j) * 128 + k] = f2bf(s);
}

// ---------------------------------------------------------------------------
// CSR build
// ---------------------------------------------------------------------------
__global__ __launch_bounds__(256) void count_deg(const int* __restrict__ ei,
                                                 int* __restrict__ deg) {
    int e = blockIdx.x * 256 + threadIdx.x;
    if (e >= E_EDGES) return;
    atomicAdd(&deg[ei[E_EDGES + e]], 1);
}

__global__ __launch_bounds__(256) void scan_p1(const int* __restrict__ deg,
                                               int* __restrict__ excl,
                                               int* __restrict__ bsum) {
    __shared__ int part[256];
    const int t = threadIdx.x;
    const int i = blockIdx.x * 256 + t;
    int v = (i < N_NODES) ? deg[i] : 0;
    part[t] = v;
    __syncthreads();
#pragma unroll
    for (int off = 1; off < 256; off <<= 1) {
        int u = (t >= off) ? part[t - off] : 0;
        __syncthreads();
        part[t] += u;
        __syncthreads();
    }
    if (i < N_NODES) excl[i] = part[t] - v;
    if (t == 255) bsum[blockIdx.x] = part[255];
}

__global__ __launch_bounds__(256) void scan_p2(int* __restrict__ bsum,
                                               int* __restrict__ rowptrN) {
    __shared__ int part[256];
    const int t = threadIdx.x;
    int v = (t < NBLK_SCAN) ? bsum[t] : 0;
    part[t] = v;
    __syncthreads();
#pragma unroll
    for (int off = 1; off < 256; off <<= 1) {
        int u = (t >= off) ? part[t - off] : 0;
        __syncthreads();
        part[t] += u;
        __syncthreads();
    }
    if (t < NBLK_SCAN) bsum[t] = part[t] - v;
    if (t == 255) *rowptrN = part[255];
}

__global__ __launch_bounds__(256) void scan_p3(const int* __restrict__ bsum,
                                               int* __restrict__ rowptr,
                                               int* __restrict__ cursor) {
    int i = blockIdx.x * 256 + threadIdx.x;
    if (i >= N_NODES) return;
    int r = rowptr[i] + bsum[blockIdx.x];
    rowptr[i] = r;
    cursor[i] = r;
}

// Packed fill: one 8B store per edge (src, weight)
__global__ __launch_bounds__(256) void fill_csr(const int* __restrict__ ei,
                                                const float* __restrict__ ew,
                                                int* __restrict__ cursor,
                                                int2* __restrict__ sEdge) {
    int e = blockIdx.x * 256 + threadIdx.x;
    if (e >= E_EDGES) return;
    int dst = ei[E_EDGES + e];
    int pos = atomicAdd(&cursor[dst], 1);
    int2 pk;
    pk.x = ei[e];
    pk.y = __float_as_int(ew[e]);
    sEdge[pos] = pk;
}

// ---------------------------------------------------------------------------
// gh[n,:] = sum_e w[e]*h[src[e],:]
// 4 lane-quarters own 4 edges in flight; indices prefetched 2 ahead, row data
// 1 ahead. Lane li handles 8 features (16B). shfl reduce across quarters.
// ---------------------------------------------------------------------------
__global__ __launch_bounds__(256) void gather_agg_bf16(const unsigned short* __restrict__ m,
                                                       const int* __restrict__ rowptr,
                                                       const int2* __restrict__ sEdge,
                                                       unsigned short* __restrict__ agg) {
    int wid = (blockIdx.x * 256 + threadIdx.x) >> 6;
    if (wid >= N_NODES) return;
    int lane = threadIdx.x & 63;
    int q = lane >> 4, li = lane & 15;
    int f0 = li << 3;          // 8 bf16 per lane
    int e0 = rowptr[wid], e1 = rowptr[wid + 1];
    float acc[8] = {0.f, 0.f, 0.f, 0.f, 0.f, 0.f, 0.f, 0.f};
    int e = e0 + q;
    bf16x8 v = {0, 0, 0, 0, 0, 0, 0, 0};
    float w0 = 0.f;
    if (e < e1) {
        int2 pk0 = sEdge[e];
        w0 = __int_as_float(pk0.y);
        v = ldfrag(m + (size_t)pk0.x * KD + f0);
    }
    int2 pk1 = make_int2(0, 0);
    if (e + 4 < e1) pk1 = sEdge[e + 4];
    for (; e < e1; e += 4) {
        float wc = w0;
        bf16x8 vc = v;
        if (e + 4 < e1) {
            w0 = __int_as_float(pk1.y);
            v = ldfrag(m + (size_t)pk1.x * KD + f0);   // row e+4 (idx ready)
        }
        if (e + 8 < e1) pk1 = sEdge[e + 8];            // idx e+8
#pragma unroll
        for (int j = 0; j < 8; ++j)
            acc[j] += wc * bf2f((unsigned short)vc[j]);
    }
#pragma unroll
    for (int j = 0; j < 8; ++j) {
        acc[j] += __shfl_xor(acc[j], 16, 64);
        acc[j] += __shfl_xor(acc[j], 32, 64);
    }
    if (q == 0) {
        bf16x8 o;
#pragma unroll
        for (int j = 0; j < 8; ++j) o[j] = (short)f2bf(acc[j]);
        *(bf16x8*)(agg + (size_t)wid * KD + f0) = o;
    }
}

// ---------------------------------------------------------------------------
// Fused GRU, col-split 8, XCD-aware persistent grid; pipelined A- AND hv-loads.
// ---------------------------------------------------------------------------
__global__ __launch_bounds__(256) void gru_fused(const unsigned short* __restrict__ Agg,
                                                 const unsigned short* __restrict__ Hin,
                                                 unsigned short* __restrict__ Hout,
                                                 const unsigned short* __restrict__ Wih,
                                                 const unsigned short* __restrict__ Whh,
                                                 const float* __restrict__ bih,
                                                 const float* __restrict__ bhh) {
    int cg, rb;
    cell_decode(blockIdx.x, cg, rb);
    __shared__ unsigned short lds[24 * 512];   // 24 KB
    const int lane = threadIdx.x & 63, wave = threadIdx.x >> 6;
    const int rl = lane & 15, kg = lane >> 4;
    const int col0 = cg * 16;
    for (int q = wave; q < 24; q += 4) {
        int s = q >> 2, kk = q & 3;
        const unsigned short* src = (s < 3 ? Wih + (size_t)s * 128 * KD
                                           : Whh + (size_t)(s - 3) * 128 * KD)
                                    + (size_t)(col0 + rl) * KD + kk * 32 + kg * 8;
        stage_frag(src, lds + q * 512);
    }
    __syncthreads();
    const int col = col0 + rl;
    const float b_ir = bih[col], b_iz = bih[128 + col], b_in = bih[256 + col];
    const float b_hr = bhh[col], b_hz = bhh[128 + col], b_hn = bhh[256 + col];
    int rt = rb * 4 + wave;
    if (rt >= RT_TILES) return;
    bf16x8 a1[4], a2[4];
    unsigned short hvc[4];
#pragma unroll
    for (int kk = 0; kk < 4; ++kk) {
        a1[kk] = ldfrag(Agg + ((size_t)rt * 16 + rl) * KD + kk * 32 + kg * 8);
        a2[kk] = ldfrag(Hin + ((size_t)rt * 16 + rl) * KD + kk * 32 + kg * 8);
    }
#pragma unroll
    for (int p = 0; p < 4; ++p)
        hvc[p] = Hin[(size_t)(rt * 16 + kg * 4 + p) * KD + col];
    while (rt < RT_TILES) {
        const int rtn = rt + CELL_STRIDE;
        bf16x8 n1[4], n2[4];
        unsigned short hvn[4];
        if (rtn < RT_TILES) {
#pragma unroll
            for (int kk = 0; kk < 4; ++kk) {
                n1[kk] = ldfrag(Agg + ((size_t)rtn * 16 + rl) * KD + kk * 32 + kg * 8);
                n2[kk] = ldfrag(Hin + ((size_t)rtn * 16 + rl) * KD + kk * 32 + kg * 8);
            }
#pragma unroll
            for (int p = 0; p < 4; ++p)
                hvn[p] = Hin[(size_t)(rtn * 16 + kg * 4 + p) * KD + col];
        }
        f32x4 ir = {0.f,0.f,0.f,0.f}, iz = ir, in_ = ir, hr = ir, hz = ir, hn = ir;
#pragma unroll
        for (int kk = 0; kk < 4; ++kk) {
            ir  = __builtin_amdgcn_mfma_f32_16x16x32_bf16(a1[kk], ldfrag(lds + (0*4+kk)*512 + lane*8), ir,  0, 0, 0);
            iz  = __builtin_amdgcn_mfma_f32_16x16x32_bf16(a1[kk], ldfrag(lds + (1*4+kk)*512 + lane*8), iz,  0, 0, 0);
            in_ = __builtin_amdgcn_mfma_f32_16x16x32_bf16(a1[kk], ldfrag(lds + (2*4+kk)*512 + lane*8), in_, 0, 0, 0);
            hr  = __builtin_amdgcn_mfma_f32_16x16x32_bf16(a2[kk], ldfrag(lds + (3*4+kk)*512 + lane*8), hr,  0, 0, 0);
            hz  = __builtin_amdgcn_mfma_f32_16x16x32_bf16(a2[kk], ldfrag(lds + (4*4+kk)*512 + lane*8), hz,  0, 0, 0);
            hn  = __builtin_amdgcn_mfma_f32_16x16x32_bf16(a2[kk], ldfrag(lds + (5*4+kk)*512 + lane*8), hn,  0, 0, 0);
        }
#pragma unroll
        for (int p = 0; p < 4; ++p) {
            int row = rt * 16 + kg * 4 + p;
            float r = fsig(ir[p] + b_ir + hr[p] + b_hr);
            float z = fsig(iz[p] + b_iz + hz[p] + b_hz);
            float nc = ftanh(in_[p] + b_in + r * (hn[p] + b_hn));
            float hv = bf2f(hvc[p]);
            Hout[(size_t)row * KD + col] = f2bf((1.f - z) * nc + z * hv);
        }
        rt = rtn;
#pragma unroll
        for (int kk = 0; kk < 4; ++kk) { a1[kk] = n1[kk]; a2[kk] = n2[kk]; }
#pragma unroll
        for (int p = 0; p < 4; ++p) hvc[p] = hvn[p];
    }
}

// ---------------------------------------------------------------------------
// Fused LSTM, col-split 8, XCD-aware persistent grid; pipelined A/Cx loads.
// h_out/c_out use non-temporal stores (never re-read) to keep L2 for inputs.
// ---------------------------------------------------------------------------
__global__ __launch_bounds__(256) void lstm_fused(const unsigned short* __restrict__ Hh,
                                                  const unsigned short* __restrict__ Hx,
                                                  const float* __restrict__ Cx,
                                                  const unsigned short* __restrict__ Wih,
                                                  const unsigned short* __restrict__ Whh,
                                                  const float* __restrict__ bih,
                                                  const float* __restrict__ bhh,
                                                  float* __restrict__ h_out,
                                                  float* __restrict__ c_out,
                                                  unsigned short* __restrict__ Hrelu) {
    int cg, rb;
    cell_decode(blockIdx.x, cg, rb);
    __shared__ unsigned short lds[32 * 512];   // 32 KB
    const int lane = threadIdx.x & 63, wave = threadIdx.x >> 6;
    const int rl = lane & 15, kg = lane >> 4;
    const int col0 = cg * 16;
    for (int q = wave; q < 32; q += 4) {
        int s = q >> 2, kk = q & 3;
        const unsigned short* src = (s < 4 ? Wih + (size_t)s * 128 * KD
                                           : Whh + (size_t)(s - 4) * 128 * KD)
                                    + (size_t)(col0 + rl) * KD + kk * 32 + kg * 8;
        stage_frag(src, lds + q * 512);
    }
    __syncthreads();
    const int col = col0 + rl;
    const float b_i = bih[col] + bhh[col];
    const float b_f = bih[128 + col] + bhh[128 + col];
    const float b_g = bih[256 + col] + bhh[256 + col];
    const float b_o = bih[384 + col] + bhh[384 + col];
    int rt = rb * 4 + wave;
    if (rt >= RT_TILES) return;
    bf16x8 a1[4], a2[4];
    float cpre[4];
#pragma unroll
    for (int kk = 0; kk < 4; ++kk) {
        a1[kk] = ldfrag(Hh + ((size_t)rt * 16 + rl) * KD + kk * 32 + kg * 8);
        a2[kk] = ldfrag(Hx + ((size_t)rt * 16 + rl) * KD + kk * 32 + kg * 8);
    }
#pragma unroll
    for (int p = 0; p < 4; ++p)
        cpre[p] = Cx[(size_t)(rt * 16 + kg * 4 + p) * KD + col];
    while (rt < RT_TILES) {
        const int rtn = rt + CELL_STRIDE;
        bf16x8 n1[4], n2[4];
        float cnx[4];
        if (rtn < RT_TILES) {
#pragma unroll
            for (int kk = 0; kk < 4; ++kk) {
                n1[kk] = ldfrag(Hh + ((size_t)rtn * 16 + rl) * KD + kk * 32 + kg * 8);
                n2[kk] = ldfrag(Hx + ((size_t)rtn * 16 + rl) * KD + kk * 32 + kg * 8);
            }
#pragma unroll
            for (int p = 0; p < 4; ++p)
                cnx[p] = Cx[(size_t)(rtn * 16 + kg * 4 + p) * KD + col];
        }
        f32x4 gi = {0.f,0.f,0.f,0.f}, gf = gi, gg = gi, go = gi;
        f32x4 hi = gi, hf = gi, hg = gi, ho = gi;
#pragma unroll
        for (int kk = 0; kk < 4; ++kk) {
            gi = __builtin_amdgcn_mfma_f32_16x16x32_bf16(a1[kk], ldfrag(lds + (0*4+kk)*512 + lane*8), gi, 0, 0, 0);
            gf = __builtin_amdgcn_mfma_f32_16x16x32_bf16(a1[kk], ldfrag(lds + (1*4+kk)*512 + lane*8), gf, 0, 0, 0);
            gg = __builtin_amdgcn_mfma_f32_16x16x32_bf16(a1[kk], ldfrag(lds + (2*4+kk)*512 + lane*8), gg, 0, 0, 0);
            go = __builtin_amdgcn_mfma_f32_16x16x32_bf16(a1[kk], ldfrag(lds + (3*4+kk)*512 + lane*8), go, 0, 0, 0);
            hi = __builtin_amdgcn_mfma_f32_16x16x32_bf16(a2[kk], ldfrag(lds + (4*4+kk)*512 + lane*8), hi, 0, 0, 0);
            hf = __builtin_amdgcn_mfma_f32_16x16x32_bf16(a2[kk], ldfrag(lds + (5*4+kk)*512 + lane*8), hf, 0, 0, 0);
            hg = __builtin_amdgcn_mfma_f32_16x16x32_bf16(a2[kk], ldfrag(lds + (6*4+kk)*512 + lane*8), hg, 0, 0, 0);
            ho = __builtin_amdgcn_mfma_f32_16x16x32_bf16(a2[kk], ldfrag(lds + (7*4+kk)*512 + lane*8), ho, 0, 0, 0);
        }
#pragma unroll
        for (int p = 0; p < 4; ++p) {
            int row = rt * 16 + kg * 4 + p;
            size_t idx = (size_t)row * KD + col;
            float ig = fsig(gi[p] + hi[p] + b_i);
            float fg = fsig(gf[p] + hf[p] + b_f);
            float gv = ftanh(gg[p] + hg[p] + b_g);
            float og = fsig(go[p] + ho[p] + b_o);
            float c = fg * cpre[p] + ig * gv;
            float hn = og * ftanh(c);
            __builtin_nontemporal_store(c, c_out + idx);
            __builtin_nontemporal_store(hn, h_out + idx);
            Hrelu[idx] = f2bf(fmaxf(hn, 0.f));
        }
        rt = rtn;
#pragma unroll
        for (int kk = 0; kk < 4; ++kk) { a1[kk] = n1[kk]; a2[kk] = n2[kk]; }
#pragma unroll
        for (int p = 0; p < 4; ++p) cpre[p] = cnx[p];
    }
}

// ---------------------------------------------------------------------------
// head: out[N][64] = hrelu @ lin_wᵀ + lin_b; nt stores (out never re-read).
// ---------------------------------------------------------------------------
__global__ __launch_bounds__(256) void head_gemm(const unsigned short* __restrict__ Hr,
                                                 const unsigned short* __restrict__ LinW,
                                                 const float* __restrict__ lin_b,
                                                 float* __restrict__ Out) {
    __shared__ unsigned short wlds[16 * 512];
    const int lane = threadIdx.x & 63, wave = threadIdx.x >> 6;
    const int rl = lane & 15, kg = lane >> 4;
    for (int f = wave; f < 16; f += 4) {
        int jt = f >> 2, kk = f & 3;
        stage_frag(LinW + (size_t)(jt * 16 + rl) * KD + kk * 32 + kg * 8, wlds + f * 512);
    }
    __syncthreads();
    const int stride = gridDim.x << 2;
    int rt = blockIdx.x * 4 + wave;
    if (rt >= RT_TILES) return;
    bf16x8 a[4];
#pragma unroll
    for (int kk = 0; kk < 4; ++kk)
        a[kk] = ldfrag(Hr + ((size_t)rt * 16 + rl) * KD + kk * 32 + kg * 8);
    while (rt < RT_TILES) {
        const int rtn = rt + stride;
        bf16x8 an[4];
        if (rtn < RT_TILES) {
#pragma unroll
            for (int kk = 0; kk < 4; ++kk)
                an[kk] = ldfrag(Hr + ((size_t)rtn * 16 + rl) * KD + kk * 32 + kg * 8);
        }
#pragma unroll
        for (int jt = 0; jt < 4; ++jt) {
            f32x4 acc = {0.f, 0.f, 0.f, 0.f};
#pragma unroll
            for (int kk = 0; kk < 4; ++kk)
                acc = __builtin_amdgcn_mfma_f32_16x16x32_bf16(
                    a[kk], ldfrag(wlds + (jt * 4 + kk) * 512 + lane * 8), acc, 0, 0, 0);
            int col = jt * 16 + rl;
            float b = lin_b[col];
#pragma unroll
            for (int p = 0; p < 4; ++p)
                __builtin_nontemporal_store(acc[p] + b,
                    Out + (size_t)(rt * 16 + kg * 4 + p) * 64 + col);
        }
        rt = rtn;
#pragma unroll
        for (int kk = 0; kk < 4; ++kk) a[kk] = an[kk];
    }
}

extern "C" void kernel_launch(void* const* d_in, const int* in_sizes, int n_in,
                              void* d_out, int out_size, void* d_ws, size_t ws_size,
                              hipStream_t stream) {
    const float* x        = (const float*)d_in[0];
    const int*   ei       = (const int*)d_in[1];
    const float* ew       = (const float*)d_in[2];
    const float* H        = (const float*)d_in[3];
    const float* C        = (const float*)d_in[4];
    const float* ggc_w    = (const float*)d_in[5];
    const float* gru_wih  = (const float*)d_in[6];
    const float* gru_whh  = (const float*)d_in[7];
    const float* gru_bih  = (const float*)d_in[8];
    const float* gru_bhh  = (const float*)d_in[9];
    const float* lstm_wih = (const float*)d_in[10];
    const float* lstm_whh = (const float*)d_in[11];
    const float* lstm_bih = (const float*)d_in[12];
    const float* lstm_bhh = (const float*)d_in[13];
    const float* lin_w    = (const float*)d_in[14];
    const float* lin_b    = (const float*)d_in[15];

    float* out_head = (float*)d_out;
    float* h_out = out_head + (size_t)N_NODES * 64;
    float* c_out = h_out + (size_t)N_NODES * KD;

    char* w = (char*)d_ws;
    unsigned short* hb    = (unsigned short*)w; w += (size_t)N_NODES * KD * 2;
    unsigned short* hb1   = (unsigned short*)w; w += (size_t)N_NODES * KD * 2;
    unsigned short* Hxb   = (unsigned short*)w; w += (size_t)N_NODES * KD * 2;
    unsigned short* mb    = (unsigned short*)w; w += (size_t)N_NODES * KD * 2;  // Hrelu
    unsigned short* aggb  = (unsigned short*)w; w += (size_t)N_NODES * KD * 2;  // gathered h
    unsigned short* WfT   = (unsigned short*)w; w += 2 * 384 * KD * 2;          // fused Wg·Wih^T
    unsigned short* whhb  = (unsigned short*)w; w += 384 * KD * 2;
    unsigned short* lwihb = (unsigned short*)w; w += 512 * KD * 2;
    unsigned short* lwhhb = (unsigned short*)w; w += 512 * KD * 2;
    unsigned short* linwb = (unsigned short*)w; w += 64 * KD * 2;
    int*   rowptr = (int*)w; w += 50304 * 4;
    int*   cursor = (int*)w; w += 50304 * 4;
    int*   bsum   = (int*)w; w += 256 * 4;
    int2*  sEdge  = (int2*)w; w += (size_t)E_EDGES * 8;   // packed (src, weight)

    dim3 blk(256);
    const int EB = (E_EDGES + 255) / 256;
    const int NF4 = N_NODES * KD / 4;

    cvt_xh<<<(2 * NF4 + 255) / 256, blk, 0, stream>>>(x, H, hb, Hxb, NF4);
    cvt_weights<<<(47104 + 255) / 256, blk, 0, stream>>>(
        gru_whh, lstm_wih, lstm_whh, lin_w,
        whhb, lwihb, lwhhb, linwb);
    fuse_wg_wih<<<dim3(384, 2), 128, 0, stream>>>(ggc_w, gru_wih, WfT);

    hipMemsetAsync(cursor, 0, N_NODES * sizeof(int), stream);
    count_deg<<<EB, blk, 0, stream>>>(ei, cursor);
    scan_p1<<<NBLK_SCAN, blk, 0, stream>>>(cursor, rowptr, bsum);
    scan_p2<<<1, blk, 0, stream>>>(bsum, rowptr + N_NODES);
    scan_p3<<<NBLK_SCAN, blk, 0, stream>>>(bsum, rowptr, cursor);
    fill_csr<<<EB, blk, 0, stream>>>(ei, ew, cursor, sEdge);

    // layer 0
    gather_agg_bf16<<<(N_NODES * 64 + 255) / 256, blk, 0, stream>>>(
        hb, rowptr, sEdge, aggb);
    gru_fused<<<CELL_BLOCKS, blk, 0, stream>>>(aggb, hb, hb1,
                                               WfT, whhb, gru_bih, gru_bhh);
    // layer 1
    gather_agg_bf16<<<(N_NODES * 64 + 255) / 256, blk, 0, stream>>>(
        hb1, rowptr, sEdge, aggb);
    gru_fused<<<CELL_BLOCKS, blk, 0, stream>>>(aggb, hb1, hb,
                                               WfT + (size_t)384 * KD, whhb, gru_bih, gru_bhh);

    lstm_fused<<<CELL_BLOCKS, blk, 0, stream>>>(hb, Hxb, C, lwihb, lwhhb,
                                                lstm_bih, lstm_bhh, h_out, c_out, mb);
    head_gemm<<<391, blk, 0, stream>>>(mb, linwb, lin_b, out_head);
}